// Round 5
// baseline (384.377 us; speedup 1.0000x reference)
//
#include <hip/hip_runtime.h>
#include <hip/hip_bf16.h>
#include <math.h>

// SAM2 MultiScale Block — round 4: fused window mega-kernel + mlp K-split.
// DIM=112(K pad 128), DIM_OUT=224, HEADS=4, HD=56, WS=8, QS=2, MLP=896
//
// ws layout (bytes):
//   hs_bf @ 0          : 131072x112 bf16 = 29,360,128
//   hs2   @ 29,360,128 : 32768x224 f32   = 29,360,128  (write-once by attn_mega)
//   wF    @ 73,400,320 : frag-packed bf16 weights (elems):
//     qkvF 704x128 @ +0       rpF 224x128 @ +90112   apF 224x224 @ +118784
//     m1F  896x224 @ +168960  m2F 224x896 @ +369664  (end 570368)
// Frag order: elem (n,k) -> tile=(n/16)*KT+(k/32); flat=(tile*64+lane)*8+j
//   with lane=((k%32)/8)*16+(n%16), j=k%8  => one wave B-frag = 1KB contiguous.

#define SCALE_A 0.13363062095621219f  // 56^-0.5

typedef __attribute__((ext_vector_type(8))) short short8;
typedef __attribute__((ext_vector_type(4))) float f32x4;

__device__ inline short f2bf(float x) {
  union { float f; unsigned u; } v; v.f = x;
  unsigned r = v.u + 0x7fff + ((v.u >> 16) & 1);
  return (short)(r >> 16);
}
__device__ inline float b2f(short s) {
  union { float f; unsigned u; } v;
  v.u = ((unsigned)(unsigned short)s) << 16;
  return v.f;
}
__device__ inline float gelu_exact(float x) {
  return 0.5f * x * (1.f + erff(x * 0.70710678118f));
}

// ------------------------------------------- weight cast to frag order
__global__ void cast_w_kernel(const float* __restrict__ qkv_w,
                              const float* __restrict__ rp_w,
                              const float* __restrict__ ap_w,
                              const float* __restrict__ m1_w,
                              const float* __restrict__ m2_w,
                              short* __restrict__ wF) {
  int tid = blockIdx.x * blockDim.x + threadIdx.x;
  int stride = gridDim.x * blockDim.x;
  // qkvF: permuted cols cp = h*176 + cl; cl: [q 0..55|k 56..111|v 112..167|pad]
  for (int e = tid; e < 90112; e += stride) {
    int j = e & 7, lr = (e >> 3) & 15, lqq = (e >> 7) & 3, tile = e >> 9;
    int kt = tile & 3, nt = tile >> 2;
    int cp = nt * 16 + lr;
    int h = cp / 176, cl = cp % 176;
    int k = kt * 32 + lqq * 8 + j;
    float val = 0.f;
    if (k < 112 && cl < 168) {
      int bcol = (cl < 56) ? (h * 56 + cl)
               : (cl < 112) ? (224 + h * 56 + (cl - 56))
                            : (448 + h * 56 + (cl - 112));
      val = qkv_w[k * 672 + bcol];
    }
    wF[e] = f2bf(val);
  }
  for (int e = tid; e < 28672; e += stride) {  // rpF: N=224, KT=4
    int j = e & 7, lr = (e >> 3) & 15, lqq = (e >> 7) & 3, tile = e >> 9;
    int kt = tile & 3, nt = tile >> 2;
    int n = nt * 16 + lr, k = kt * 32 + lqq * 8 + j;
    wF[90112 + e] = (k < 112) ? f2bf(rp_w[k * 224 + n]) : (short)0;
  }
  for (int e = tid; e < 50176; e += stride) {  // apF: N=224, KT=7
    int j = e & 7, lr = (e >> 3) & 15, lqq = (e >> 7) & 3, tile = e >> 9;
    int kt = tile % 7, nt = tile / 7;
    int n = nt * 16 + lr, k = kt * 32 + lqq * 8 + j;
    wF[118784 + e] = f2bf(ap_w[k * 224 + n]);
  }
  for (int e = tid; e < 200704; e += stride) {  // m1F: N=896, KT=7
    int j = e & 7, lr = (e >> 3) & 15, lqq = (e >> 7) & 3, tile = e >> 9;
    int kt = tile % 7, nt = tile / 7;
    int n = nt * 16 + lr, k = kt * 32 + lqq * 8 + j;
    wF[168960 + e] = f2bf(m1_w[k * 896 + n]);
  }
  for (int e = tid; e < 200704; e += stride) {  // m2F: N=224, KT=28
    int j = e & 7, lr = (e >> 3) & 15, lqq = (e >> 7) & 3, tile = e >> 9;
    int kt = tile % 28, nt = tile / 28;
    int n = nt * 16 + lr, k = kt * 32 + lqq * 8 + j;
    wF[369664 + e] = f2bf(m2_w[k * 224 + n]);
  }
}

// ---------------------------------------------------------------- LN1 -> bf16
__global__ __launch_bounds__(256) void ln1_kernel(
    const float* __restrict__ x, const float* __restrict__ g,
    const float* __restrict__ b, short* __restrict__ hs) {
  int row = blockIdx.x * 4 + (threadIdx.x >> 6);
  int lane = threadIdx.x & 63;
  const float* rp = x + (size_t)row * 112;
  float v0 = rp[lane];
  float v1 = (lane < 48) ? rp[64 + lane] : 0.f;
  float s = v0 + v1;
  #pragma unroll
  for (int off = 32; off; off >>= 1) s += __shfl_down(s, off);
  s = __shfl(s, 0);
  float mean = s * (1.f / 112.f);
  float d0 = v0 - mean;
  float d1 = (lane < 48) ? (v1 - mean) : 0.f;
  float s2 = d0 * d0 + d1 * d1;
  #pragma unroll
  for (int off = 32; off; off >>= 1) s2 += __shfl_down(s2, off);
  s2 = __shfl(s2, 0);
  float rs = rsqrtf(s2 * (1.f / 112.f) + 1e-6f);
  short* op = hs + (size_t)row * 112;
  op[lane] = f2bf(d0 * rs * g[lane] + b[lane]);
  if (lane < 48) op[64 + lane] = f2bf(d1 * rs * g[64 + lane] + b[64 + lane]);
}

// ===== fused window kernel: respool + qkv + attention + attn_proj + residual
// Waves own N-tiles and iterate all 4 M-tiles (A-frags hoisted, B loaded once).
__global__ __launch_bounds__(256, 3) void attn_mega_kernel(
    const short* __restrict__ hs, const short* __restrict__ qkvF,
    const float* __restrict__ qkv_b, const short* __restrict__ rpF,
    const float* __restrict__ rp_b, const short* __restrict__ apF,
    const float* __restrict__ ap_b, float* __restrict__ hs2) {
  __shared__ alignas(16) short w_s[64 * 136];   // 17408 B window tokens (pool order)
  __shared__ alignas(16) short kp_s[64 * 72];   //  9216 B k; P overlays rows 0..15
  __shared__ alignas(16) short vT_s[64 * 72];   //  9216 B hd x keys
  __shared__ alignas(16) short q_s[16 * 72];    //  2304 B pooled q * scale
  __shared__ alignas(16) short o_s[16 * 232];   //  7424 B concat o (all heads)
  __shared__ alignas(16) short res_s[16 * 224]; //  7168 B res_proj+pool (bf16)
  __shared__ float pm_s[16][4];                 //   256 B
  __shared__ float ps_s[16][4];                 //   256 B => 53,248 B total
  int win = blockIdx.x;                         // 2048
  int nw = win & 15, nh = (win >> 4) & 15, b = win >> 8;
  int tid = threadIdx.x;
  int wave = tid >> 6, lane = tid & 63, lrow = lane & 15, lq = lane >> 4;

  for (int e = tid; e < 1024; e += 256) {
    int m = e >> 4, c = e & 15;
    short8* dst = (short8*)&w_s[m * 136 + c * 8];
    if (c < 14) {
      int p = m >> 2, r = m & 3;
      int tr = (p >> 2) * 2 + (r >> 1), tc = (p & 3) * 2 + (r & 1);
      size_t token = ((size_t)(b * 128 + nh * 8 + tr)) * 128 + (nw * 8 + tc);
      *dst = *(const short8*)(hs + token * 112 + c * 8);
    } else {
      short8 z = {0, 0, 0, 0, 0, 0, 0, 0};
      *dst = z;
    }
  }
  for (int e = tid; e < 512; e += 256) kp_s[(e >> 3) * 72 + 56 + (e & 7)] = 0;
  if (tid < 128) q_s[(tid >> 3) * 72 + 56 + (tid & 7)] = 0;
  __syncthreads();

  // hoist A-frags for ALL 4 M-tiles (shared by respool + qkv): 16 short8
  short8 Aw[4][4];
  #pragma unroll
  for (int mt = 0; mt < 4; ++mt)
    #pragma unroll
    for (int kt = 0; kt < 4; ++kt)
      Aw[mt][kt] = *(const short8*)&w_s[(mt * 16 + lrow) * 136 + kt * 32 + lq * 8];

  // N-tile ownership
  int t0_14 = (wave < 2) ? wave * 4 : 8 + (wave - 2) * 3;   // 14-tile split 4,4,3,3
  int cnt_14 = (wave < 2) ? 4 : 3;
  int t0_q = wave * 3;                                       // 11-tile split 3,3,3,2
  int cnt_q = (wave == 3) ? 2 : 3;

  // ---- respool: res = maxpool2(hs @ rp_w + rp_b) for this window's 16 pixels
  for (int i = 0; i < cnt_14; ++i) {
    int t = t0_14 + i;
    int col = t * 16 + lrow;
    f32x4 ac[4] = {{0.f,0.f,0.f,0.f},{0.f,0.f,0.f,0.f},{0.f,0.f,0.f,0.f},{0.f,0.f,0.f,0.f}};
    #pragma unroll
    for (int kt = 0; kt < 4; ++kt) {
      short8 bw = *(const short8*)(rpF + ((t * 4 + kt) * 64 + lane) * 8);
      #pragma unroll
      for (int mt = 0; mt < 4; ++mt)
        ac[mt] = __builtin_amdgcn_mfma_f32_16x16x32_bf16(Aw[mt][kt], bw, ac[mt], 0, 0, 0);
    }
    float bi = rp_b[col];
    #pragma unroll
    for (int mt = 0; mt < 4; ++mt) {
      float mx = fmaxf(fmaxf(ac[mt][0], ac[mt][1]), fmaxf(ac[mt][2], ac[mt][3])) + bi;
      res_s[(mt * 4 + lq) * 224 + col] = f2bf(mx);
    }
  }

  // ---- per-head attention
  for (int h = 0; h < 4; ++h) {
    if (h && tid < 128) kp_s[(tid >> 3) * 72 + 56 + (tid & 7)] = 0;  // re-zero P-clobbered pad
    // qkv: wave owns its N-tiles, all 4 M-tiles
    for (int i = 0; i < cnt_q; ++i) {
      int t = t0_q + i;
      int cl = t * 16 + lrow;
      f32x4 ac[4] = {{0.f,0.f,0.f,0.f},{0.f,0.f,0.f,0.f},{0.f,0.f,0.f,0.f},{0.f,0.f,0.f,0.f}};
      #pragma unroll
      for (int kt = 0; kt < 4; ++kt) {
        short8 bw = *(const short8*)(qkvF + (((h * 11 + t) * 4 + kt) * 64 + lane) * 8);
        #pragma unroll
        for (int mt = 0; mt < 4; ++mt)
          ac[mt] = __builtin_amdgcn_mfma_f32_16x16x32_bf16(Aw[mt][kt], bw, ac[mt], 0, 0, 0);
      }
      if (cl < 168) {
        int bcol = (cl < 56) ? (h * 56 + cl)
                 : (cl < 112) ? (224 + h * 56 + (cl - 56))
                              : (448 + h * 56 + (cl - 112));
        float bias = qkv_b[bcol];
        if (cl < 56) {
          #pragma unroll
          for (int mt = 0; mt < 4; ++mt) {
            float mx = fmaxf(fmaxf(ac[mt][0], ac[mt][1]), fmaxf(ac[mt][2], ac[mt][3])) + bias;
            q_s[(mt * 4 + lq) * 72 + cl] = f2bf(mx * SCALE_A);
          }
        } else if (cl < 112) {
          #pragma unroll
          for (int mt = 0; mt < 4; ++mt)
            #pragma unroll
            for (int r = 0; r < 4; ++r)
              kp_s[(mt * 16 + lq * 4 + r) * 72 + (cl - 56)] = f2bf(ac[mt][r] + bias);
        } else {
          #pragma unroll
          for (int mt = 0; mt < 4; ++mt)
            #pragma unroll
            for (int r = 0; r < 4; ++r)
              vT_s[(cl - 112) * 72 + mt * 16 + lq * 4 + r] = f2bf(ac[mt][r] + bias);
        }
      }
    }
    __syncthreads();  // A: q/k/v ready
    // scores: wave owns keys [wave*16, +16)
    f32x4 sc = {0.f, 0.f, 0.f, 0.f};
    #pragma unroll
    for (int kt = 0; kt < 2; ++kt) {
      short8 a = *(const short8*)&q_s[lrow * 72 + kt * 32 + lq * 8];
      short8 bk = *(const short8*)&kp_s[(wave * 16 + lrow) * 72 + kt * 32 + lq * 8];
      sc = __builtin_amdgcn_mfma_f32_16x16x32_bf16(a, bk, sc, 0, 0, 0);
    }
    float mr[4] = {sc[0], sc[1], sc[2], sc[3]};
    #pragma unroll
    for (int off = 8; off; off >>= 1) {
      #pragma unroll
      for (int r = 0; r < 4; ++r) mr[r] = fmaxf(mr[r], __shfl_xor(mr[r], off, 16));
    }
    if (lrow < 4) pm_s[lq * 4 + lrow][wave] = mr[lrow];
    __syncthreads();  // B: partial maxes ready
    float er[4], sr[4];
    #pragma unroll
    for (int r = 0; r < 4; ++r) {
      int row = lq * 4 + r;
      float gm = fmaxf(fmaxf(pm_s[row][0], pm_s[row][1]),
                       fmaxf(pm_s[row][2], pm_s[row][3]));
      er[r] = __expf(sc[r] - gm);
      sr[r] = er[r];
    }
    #pragma unroll
    for (int off = 8; off; off >>= 1) {
      #pragma unroll
      for (int r = 0; r < 4; ++r) sr[r] += __shfl_xor(sr[r], off, 16);
    }
    if (lrow < 4) ps_s[lq * 4 + lrow][wave] = sr[lrow];
    #pragma unroll
    for (int r = 0; r < 4; ++r)
      kp_s[(lq * 4 + r) * 72 + wave * 16 + lrow] = f2bf(er[r]);  // unnormalized P
    __syncthreads();  // C: P + partial sums ready
    // PV: wave owns out cols [wave*16, +16); normalize in epilogue
    {
      int col = wave * 16 + lrow;
      f32x4 ov = {0.f, 0.f, 0.f, 0.f};
      #pragma unroll
      for (int kt = 0; kt < 2; ++kt) {
        short8 a = *(const short8*)&kp_s[lrow * 72 + kt * 32 + lq * 8];
        short8 bv = *(const short8*)&vT_s[col * 72 + kt * 32 + lq * 8];
        ov = __builtin_amdgcn_mfma_f32_16x16x32_bf16(a, bv, ov, 0, 0, 0);
      }
      if (col < 56) {
        #pragma unroll
        for (int r = 0; r < 4; ++r) {
          int row = lq * 4 + r;
          float gs = ps_s[row][0] + ps_s[row][1] + ps_s[row][2] + ps_s[row][3];
          o_s[row * 232 + h * 56 + col] = f2bf(ov[r] * (1.f / gs));
        }
      }
    }
    __syncthreads();  // D: PV done before next head rewrites LDS
  }

  // ---- attn_proj + residual -> hs2 (write-once)
  short8 Ao[7];
  #pragma unroll
  for (int kt = 0; kt < 7; ++kt)
    Ao[kt] = *(const short8*)&o_s[lrow * 232 + kt * 32 + lq * 8];
  for (int i = 0; i < cnt_14; ++i) {
    int t = t0_14 + i;
    int col = t * 16 + lrow;
    f32x4 acc = {0.f, 0.f, 0.f, 0.f};
    #pragma unroll
    for (int kt = 0; kt < 7; ++kt) {
      short8 bw = *(const short8*)(apF + ((t * 7 + kt) * 64 + lane) * 8);
      acc = __builtin_amdgcn_mfma_f32_16x16x32_bf16(Ao[kt], bw, acc, 0, 0, 0);
    }
    float bi = ap_b[col];
    #pragma unroll
    for (int r = 0; r < 4; ++r) {
      int p = lq * 4 + r;
      size_t token = ((size_t)(b * 64 + nh * 4 + (p >> 2))) * 64 + (nw * 4 + (p & 3));
      hs2[token * 224 + col] = b2f(res_s[p * 224 + col]) + acc[r] + bi;
    }
  }
}

// ------------- fused LN2 + mlp1(MFMA) + GELU + mlp2(MFMA) + residual
// 512 threads, 32 tokens; hid K-split in 2 halves -> LDS 44 KB -> 3 blocks/CU.
__global__ __launch_bounds__(512, 6) void mlp_kernel(
    const float* __restrict__ hs2, const float* __restrict__ g2,
    const float* __restrict__ b2, const short* __restrict__ m1F,
    const float* __restrict__ b1, const short* __restrict__ m2F,
    const float* __restrict__ b2b, float* __restrict__ out) {
  __shared__ alignas(16) short ln_s[32 * 232];   // 14,848 B
  __shared__ alignas(16) short hid_s[32 * 456];  // 29,184 B => 44,032 B
  int blk = blockIdx.x;  // 1024 x 32 tokens
  int tid = threadIdx.x;
  size_t base = (size_t)blk * 32 * 224;
  // LN2 in registers
  {
    int row = tid >> 4, l = tid & 15;
    const float* rp = hs2 + base + (size_t)row * 224;
    float v[14];
    float s = 0.f;
    #pragma unroll
    for (int c = 0; c < 14; ++c) { v[c] = rp[l + 16 * c]; s += v[c]; }
    #pragma unroll
    for (int off = 8; off; off >>= 1) s += __shfl_xor(s, off, 16);
    float mean = s * (1.f / 224.f);
    float s2 = 0.f;
    #pragma unroll
    for (int c = 0; c < 14; ++c) { float d = v[c] - mean; s2 = fmaf(d, d, s2); }
    #pragma unroll
    for (int off = 8; off; off >>= 1) s2 += __shfl_xor(s2, off, 16);
    float rs = rsqrtf(s2 * (1.f / 224.f) + 1e-6f);
    #pragma unroll
    for (int c = 0; c < 14; ++c) {
      int cc = l + 16 * c;
      ln_s[row * 232 + cc] = f2bf((v[c] - mean) * rs * g2[cc] + b2[cc]);
    }
  }
  __syncthreads();
  int wave = tid >> 6, lane = tid & 63, lrow = lane & 15, lq = lane >> 4;
  // GEMM1 tile sets (28 local tiles: 4 waves x 4, 4 waves x 3)
  int g1_t0 = (wave < 4) ? wave * 4 : 16 + (wave - 4) * 3;
  int g1_cnt = (wave < 4) ? 4 : 3;
  // GEMM2 tile sets (14 tiles: 6 waves x 2, 2 waves x 1)
  int g2_t0 = (wave < 6) ? wave * 2 : 12 + (wave - 6);
  int g2_cnt = (wave < 6) ? 2 : 1;
  f32x4 acc2[2][2] = {{{0.f,0.f,0.f,0.f},{0.f,0.f,0.f,0.f}},
                      {{0.f,0.f,0.f,0.f},{0.f,0.f,0.f,0.f}}};
  for (int half = 0; half < 2; ++half) {
    if (half) __syncthreads();  // prev GEMM2 reads done before hid rewrite
    // GEMM1 for hid cols [half*448, +448)
    for (int i = 0; i < g1_cnt; ++i) {
      int t = g1_t0 + i;
      int ntg = half * 28 + t;
      int cl = t * 16 + lrow;
      f32x4 a0 = {0.f,0.f,0.f,0.f}, a1 = {0.f,0.f,0.f,0.f};
      #pragma unroll
      for (int kt = 0; kt < 7; ++kt) {
        short8 A0 = *(const short8*)&ln_s[lrow * 232 + kt * 32 + lq * 8];
        short8 A1 = *(const short8*)&ln_s[(16 + lrow) * 232 + kt * 32 + lq * 8];
        short8 bw = *(const short8*)(m1F + ((size_t)(ntg * 7 + kt) * 64 + lane) * 8);
        a0 = __builtin_amdgcn_mfma_f32_16x16x32_bf16(A0, bw, a0, 0, 0, 0);
        a1 = __builtin_amdgcn_mfma_f32_16x16x32_bf16(A1, bw, a1, 0, 0, 0);
      }
      float bi = b1[ntg * 16 + lrow];
      #pragma unroll
      for (int r = 0; r < 4; ++r) {
        hid_s[(lq * 4 + r) * 456 + cl]      = f2bf(gelu_exact(a0[r] + bi));
        hid_s[(16 + lq * 4 + r) * 456 + cl] = f2bf(gelu_exact(a1[r] + bi));
      }
    }
    __syncthreads();
    // GEMM2 partial over this half's 448 hidden cols
    for (int i = 0; i < g2_cnt; ++i) {
      int t = g2_t0 + i;
      #pragma unroll 7
      for (int ktl = 0; ktl < 14; ++ktl) {
        int ktg = half * 14 + ktl;
        short8 x0 = *(const short8*)&hid_s[lrow * 456 + ktl * 32 + lq * 8];
        short8 x1 = *(const short8*)&hid_s[(16 + lrow) * 456 + ktl * 32 + lq * 8];
        short8 bw = *(const short8*)(m2F + ((size_t)(t * 28 + ktg) * 64 + lane) * 8);
        acc2[i][0] = __builtin_amdgcn_mfma_f32_16x16x32_bf16(x0, bw, acc2[i][0], 0, 0, 0);
        acc2[i][1] = __builtin_amdgcn_mfma_f32_16x16x32_bf16(x1, bw, acc2[i][1], 0, 0, 0);
      }
    }
  }
  // epilogue: bias + residual
  for (int i = 0; i < g2_cnt; ++i) {
    int t = g2_t0 + i;
    int col = t * 16 + lrow;
    float bi = b2b[col];
    #pragma unroll
    for (int r = 0; r < 4; ++r) {
      size_t i0 = base + (size_t)(lq * 4 + r) * 224 + col;
      size_t i1 = base + (size_t)(16 + lq * 4 + r) * 224 + col;
      out[i0] = hs2[i0] + acc2[i][0][r] + bi;
      out[i1] = hs2[i1] + acc2[i][1][r] + bi;
    }
  }
}

extern "C" void kernel_launch(void* const* d_in, const int* in_sizes, int n_in,
                              void* d_out, int out_size, void* d_ws, size_t ws_size,
                              hipStream_t stream) {
  const float* x    = (const float*)d_in[0];
  const float* ln1g = (const float*)d_in[1];
  const float* ln1b = (const float*)d_in[2];
  const float* qkvw = (const float*)d_in[3];
  const float* qkvb = (const float*)d_in[4];
  const float* apw  = (const float*)d_in[5];
  const float* apb  = (const float*)d_in[6];
  const float* rpw  = (const float*)d_in[7];
  const float* rpb  = (const float*)d_in[8];
  const float* ln2g = (const float*)d_in[9];
  const float* ln2b = (const float*)d_in[10];
  const float* w1   = (const float*)d_in[11];
  const float* b1   = (const float*)d_in[12];
  const float* w2   = (const float*)d_in[13];
  const float* b2   = (const float*)d_in[14];
  float* out = (float*)d_out;

  short* hs_bf = (short*)d_ws;
  float* hs2   = (float*)((char*)d_ws + 29360128);
  short* wF    = (short*)((char*)d_ws + 73400320);

  cast_w_kernel<<<1024, 256, 0, stream>>>(qkvw, rpw, apw, w1, w2, wF);
  ln1_kernel<<<32768, 256, 0, stream>>>(x, ln1g, ln1b, hs_bf);
  attn_mega_kernel<<<2048, 256, 0, stream>>>(hs_bf, wF, qkvb, wF + 90112, rpb,
                                             wF + 118784, apb, hs2);
  mlp_kernel<<<1024, 512, 0, stream>>>(hs2, ln2g, ln2b, wF + 168960, b1,
                                       wF + 369664, b2, out);
}

// Round 6
// 298.930 us; speedup vs baseline: 1.2858x; 1.2858x over previous
//
#include <hip/hip_runtime.h>
#include <hip/hip_bf16.h>
#include <math.h>

// SAM2 MultiScale Block — round 5: R3 structure restored; mlp on 32x32x16 MFMA.
// DIM=112(K pad 128), DIM_OUT=224, HEADS=4, HD=56, WS=8, QS=2, MLP=896
//
// ws layout (bytes):
//   hs_bf @ 0          : 131072x112 bf16 = 29,360,128
//   hs2   @ 29,360,128 : 32768x224 f32   = 29,360,128
//   o_bf  @ 58,720,256 : 32768x224 bf16  = 14,680,064
//   wF    @ 73,400,320 : frag-packed bf16 weights (elems):
//     qkvF 704x128 @ +0       rpF 224x128 @ +90112   apF 224x224 @ +118784
//     m1F  896x224 @ +168960  m2F 224x896 @ +369664  (end 570368)
// 16x16 frag order (qkvF/rpF/apF): (n,k) -> tile=(n/16)*KT+(k/32);
//   flat=(tile*64+lane)*8+j, lane=((k%32)/8)*16+(n%16), j=k%8.
// 32x32 frag order (m1F/m2F): (n,k) -> tile=(n/32)*KT16+(k/16);
//   flat=(tile*64+lane)*8+j, lane=((k%16)/8)*32+(n%32), j=k%8.

#define SCALE_A 0.13363062095621219f  // 56^-0.5

typedef __attribute__((ext_vector_type(8))) short short8;
typedef __attribute__((ext_vector_type(4))) float f32x4;
typedef __attribute__((ext_vector_type(16))) float f32x16;

__device__ inline short f2bf(float x) {
  union { float f; unsigned u; } v; v.f = x;
  unsigned r = v.u + 0x7fff + ((v.u >> 16) & 1);
  return (short)(r >> 16);
}
__device__ inline float gelu_exact(float x) {
  return 0.5f * x * (1.f + erff(x * 0.70710678118f));
}

// ------------------------------------------- weight cast to frag order
__global__ void cast_w_kernel(const float* __restrict__ qkv_w,
                              const float* __restrict__ rp_w,
                              const float* __restrict__ ap_w,
                              const float* __restrict__ m1_w,
                              const float* __restrict__ m2_w,
                              short* __restrict__ wF) {
  int tid = blockIdx.x * blockDim.x + threadIdx.x;
  int stride = gridDim.x * blockDim.x;
  // qkvF: permuted cols cp = h*176 + cl; cl: [q 0..55|k 56..111|v 112..167|pad]
  for (int e = tid; e < 90112; e += stride) {
    int j = e & 7, lr = (e >> 3) & 15, lqq = (e >> 7) & 3, tile = e >> 9;
    int kt = tile & 3, nt = tile >> 2;
    int cp = nt * 16 + lr;
    int h = cp / 176, cl = cp % 176;
    int k = kt * 32 + lqq * 8 + j;
    float val = 0.f;
    if (k < 112 && cl < 168) {
      int bcol = (cl < 56) ? (h * 56 + cl)
               : (cl < 112) ? (224 + h * 56 + (cl - 56))
                            : (448 + h * 56 + (cl - 112));
      val = qkv_w[k * 672 + bcol];
    }
    wF[e] = f2bf(val);
  }
  for (int e = tid; e < 28672; e += stride) {  // rpF: N=224, KT=4 (16x16)
    int j = e & 7, lr = (e >> 3) & 15, lqq = (e >> 7) & 3, tile = e >> 9;
    int kt = tile & 3, nt = tile >> 2;
    int n = nt * 16 + lr, k = kt * 32 + lqq * 8 + j;
    wF[90112 + e] = (k < 112) ? f2bf(rp_w[k * 224 + n]) : (short)0;
  }
  for (int e = tid; e < 50176; e += stride) {  // apF: N=224, KT=7 (16x16)
    int j = e & 7, lr = (e >> 3) & 15, lqq = (e >> 7) & 3, tile = e >> 9;
    int kt = tile % 7, nt = tile / 7;
    int n = nt * 16 + lr, k = kt * 32 + lqq * 8 + j;
    wF[118784 + e] = f2bf(ap_w[k * 224 + n]);
  }
  for (int e = tid; e < 200704; e += stride) {  // m1F: N=896/32, K=224/16 (32x32)
    int j = e & 7, lane = (e >> 3) & 63, unit = e >> 9;
    int kt = unit % 14, nt = unit / 14;
    int n = nt * 32 + (lane & 31), k = kt * 16 + (lane >> 5) * 8 + j;
    wF[168960 + e] = f2bf(m1_w[k * 896 + n]);
  }
  for (int e = tid; e < 200704; e += stride) {  // m2F: N=224/32, K=896/16 (32x32)
    int j = e & 7, lane = (e >> 3) & 63, unit = e >> 9;
    int kt = unit % 56, nt = unit / 56;
    int n = nt * 32 + (lane & 31), k = kt * 16 + (lane >> 5) * 8 + j;
    wF[369664 + e] = f2bf(m2_w[k * 224 + n]);
  }
}

// ---------------------------------------------------------------- LN1 -> bf16
__global__ __launch_bounds__(256) void ln1_kernel(
    const float* __restrict__ x, const float* __restrict__ g,
    const float* __restrict__ b, short* __restrict__ hs) {
  int row = blockIdx.x * 4 + (threadIdx.x >> 6);
  int lane = threadIdx.x & 63;
  const float* rp = x + (size_t)row * 112;
  float v0 = rp[lane];
  float v1 = (lane < 48) ? rp[64 + lane] : 0.f;
  float s = v0 + v1;
  #pragma unroll
  for (int off = 32; off; off >>= 1) s += __shfl_down(s, off);
  s = __shfl(s, 0);
  float mean = s * (1.f / 112.f);
  float d0 = v0 - mean;
  float d1 = (lane < 48) ? (v1 - mean) : 0.f;
  float s2 = d0 * d0 + d1 * d1;
  #pragma unroll
  for (int off = 32; off; off >>= 1) s2 += __shfl_down(s2, off);
  s2 = __shfl(s2, 0);
  float rs = rsqrtf(s2 * (1.f / 112.f) + 1e-6f);
  short* op = hs + (size_t)row * 112;
  op[lane] = f2bf(d0 * rs * g[lane] + b[lane]);
  if (lane < 48) op[64 + lane] = f2bf(d1 * rs * g[64 + lane] + b[64 + lane]);
}

// -------------------------------------- res_proj + maxpool2 (MFMA) -> hs2
__global__ __launch_bounds__(256, 4) void respool_kernel(
    const short* __restrict__ hs, const short* __restrict__ rpF,
    const float* __restrict__ bias, float* __restrict__ hs2) {
  __shared__ alignas(16) short w_s[64 * 136];
  int blk = blockIdx.x;  // 2048
  int tid = threadIdx.x;
  for (int e = tid; e < 1024; e += 256) {
    int m = e >> 4, c = e & 15;
    short8* dst = (short8*)&w_s[m * 136 + c * 8];
    if (c < 14) {
      int p = m >> 2, r = m & 3;
      int pix = blk * 16 + p;
      int bb = pix >> 12, ii = (pix >> 6) & 63, jj = pix & 63;
      size_t token = ((size_t)(bb * 128 + 2 * ii + (r >> 1))) * 128 + 2 * jj + (r & 1);
      *dst = *(const short8*)(hs + token * 112 + c * 8);
    } else {
      short8 z = {0, 0, 0, 0, 0, 0, 0, 0};
      *dst = z;
    }
  }
  __syncthreads();
  int wave = tid >> 6, lane = tid & 63, lrow = lane & 15, lq = lane >> 4;
  short8 Ar[4];
  #pragma unroll
  for (int kt = 0; kt < 4; ++kt)
    Ar[kt] = *(const short8*)&w_s[(wave * 16 + lrow) * 136 + kt * 32 + lq * 8];
  int p = wave * 4 + lq;
  for (int pr = 0; pr < 7; ++pr) {
    int c0 = pr * 32 + lrow, c1 = c0 + 16;
    f32x4 acc0 = {0.f, 0.f, 0.f, 0.f}, acc1 = {0.f, 0.f, 0.f, 0.f};
    #pragma unroll
    for (int kt = 0; kt < 4; ++kt) {
      short8 b0 = *(const short8*)(rpF + (((2 * pr) * 4 + kt) * 64 + lane) * 8);
      short8 b1 = *(const short8*)(rpF + (((2 * pr + 1) * 4 + kt) * 64 + lane) * 8);
      acc0 = __builtin_amdgcn_mfma_f32_16x16x32_bf16(Ar[kt], b0, acc0, 0, 0, 0);
      acc1 = __builtin_amdgcn_mfma_f32_16x16x32_bf16(Ar[kt], b1, acc1, 0, 0, 0);
    }
    float m0 = fmaxf(fmaxf(acc0[0], acc0[1]), fmaxf(acc0[2], acc0[3])) + bias[c0];
    float m1 = fmaxf(fmaxf(acc1[0], acc1[1]), fmaxf(acc1[2], acc1[3])) + bias[c1];
    hs2[(size_t)(blk * 16 + p) * 224 + c0] = m0;
    hs2[(size_t)(blk * 16 + p) * 224 + c1] = m1;
  }
}

// ------------------- fused windowed attention, 4 blocks/CU (R3-proven)
__global__ __launch_bounds__(256, 4) void attn_kernel(
    const short* __restrict__ hs, const short* __restrict__ qkvF,
    const float* __restrict__ qkv_b, short* __restrict__ o_bf) {
  __shared__ alignas(16) short w_s[64 * 136];   // 17408 B
  __shared__ alignas(16) short kp_s[64 * 72];   //  9216 B (k; P overlays rows 0..15)
  __shared__ alignas(16) short vT_s[64 * 72];   //  9216 B
  __shared__ alignas(16) short q_s[16 * 72];    //  2304 B
  __shared__ float pm_s[16][4];                 //   256 B
  __shared__ float ps_s[16][4];                 //   256 B  => 38656 B total
  int win = blockIdx.x;                         // 2048
  int nw = win & 15, nh = (win >> 4) & 15, b = win >> 8;
  int tid = threadIdx.x;
  int wave = tid >> 6, lane = tid & 63, lrow = lane & 15, lq = lane >> 4;

  for (int e = tid; e < 1024; e += 256) {
    int m = e >> 4, c = e & 15;
    short8* dst = (short8*)&w_s[m * 136 + c * 8];
    if (c < 14) {
      int p = m >> 2, r = m & 3;
      int tr = (p >> 2) * 2 + (r >> 1), tc = (p & 3) * 2 + (r & 1);
      size_t token = ((size_t)(b * 128 + nh * 8 + tr)) * 128 + (nw * 8 + tc);
      *dst = *(const short8*)(hs + token * 112 + c * 8);
    } else {
      short8 z = {0, 0, 0, 0, 0, 0, 0, 0};
      *dst = z;
    }
  }
  for (int e = tid; e < 512; e += 256) kp_s[(e >> 3) * 72 + 56 + (e & 7)] = 0;
  if (tid < 128) q_s[(tid >> 3) * 72 + 56 + (tid & 7)] = 0;
  __syncthreads();

  short8 Aq[4];
  #pragma unroll
  for (int kt = 0; kt < 4; ++kt)
    Aq[kt] = *(const short8*)&w_s[(wave * 16 + lrow) * 136 + kt * 32 + lq * 8];

#define QKV_EPI(CL, ACC) {                                                \
    int cl_ = (CL);                                                       \
    if (cl_ < 168) {                                                      \
      int bcol_ = (cl_ < 56) ? (h * 56 + cl_)                             \
                : (cl_ < 112) ? (224 + h * 56 + (cl_ - 56))               \
                              : (448 + h * 56 + (cl_ - 112));             \
      float bias_ = qkv_b[bcol_];                                         \
      if (cl_ < 56) {                                                     \
        float mx_ = fmaxf(fmaxf((ACC)[0], (ACC)[1]),                      \
                          fmaxf((ACC)[2], (ACC)[3])) + bias_;             \
        q_s[(wave * 4 + lq) * 72 + cl_] = f2bf(mx_ * SCALE_A);            \
      } else if (cl_ < 112) {                                             \
        _Pragma("unroll")                                                 \
        for (int r_ = 0; r_ < 4; ++r_)                                    \
          kp_s[(wave * 16 + lq * 4 + r_) * 72 + (cl_ - 56)] =             \
              f2bf((ACC)[r_] + bias_);                                    \
      } else {                                                            \
        _Pragma("unroll")                                                 \
        for (int r_ = 0; r_ < 4; ++r_)                                    \
          vT_s[(cl_ - 112) * 72 + wave * 16 + lq * 4 + r_] =              \
              f2bf((ACC)[r_] + bias_);                                    \
      }                                                                   \
    }                                                                     \
  }

  for (int h = 0; h < 4; ++h) {
    if (h && tid < 128) kp_s[(tid >> 3) * 72 + 56 + (tid & 7)] = 0;
    for (int pr = 0; pr < 5; ++pr) {
      int t0 = 2 * pr, t1 = t0 + 1;
      int cl0 = t0 * 16 + lrow, cl1 = cl0 + 16;
      f32x4 acc0 = {0.f, 0.f, 0.f, 0.f}, acc1 = {0.f, 0.f, 0.f, 0.f};
      #pragma unroll
      for (int kt = 0; kt < 4; ++kt) {
        short8 b0 = *(const short8*)(qkvF + (((h * 11 + t0) * 4 + kt) * 64 + lane) * 8);
        short8 b1 = *(const short8*)(qkvF + (((h * 11 + t1) * 4 + kt) * 64 + lane) * 8);
        acc0 = __builtin_amdgcn_mfma_f32_16x16x32_bf16(Aq[kt], b0, acc0, 0, 0, 0);
        acc1 = __builtin_amdgcn_mfma_f32_16x16x32_bf16(Aq[kt], b1, acc1, 0, 0, 0);
      }
      QKV_EPI(cl0, acc0);
      QKV_EPI(cl1, acc1);
    }
    {
      int cl = 160 + lrow;
      f32x4 acc = {0.f, 0.f, 0.f, 0.f};
      #pragma unroll
      for (int kt = 0; kt < 4; ++kt) {
        short8 bf = *(const short8*)(qkvF + (((h * 11 + 10) * 4 + kt) * 64 + lane) * 8);
        acc = __builtin_amdgcn_mfma_f32_16x16x32_bf16(Aq[kt], bf, acc, 0, 0, 0);
      }
      QKV_EPI(cl, acc);
    }
    __syncthreads();  // A: q/k/v ready
    f32x4 sc = {0.f, 0.f, 0.f, 0.f};
    #pragma unroll
    for (int kt = 0; kt < 2; ++kt) {
      short8 a = *(const short8*)&q_s[lrow * 72 + kt * 32 + lq * 8];
      short8 bk = *(const short8*)&kp_s[(wave * 16 + lrow) * 72 + kt * 32 + lq * 8];
      sc = __builtin_amdgcn_mfma_f32_16x16x32_bf16(a, bk, sc, 0, 0, 0);
    }
    float mr[4] = {sc[0], sc[1], sc[2], sc[3]};
    #pragma unroll
    for (int off = 8; off; off >>= 1) {
      #pragma unroll
      for (int r = 0; r < 4; ++r) mr[r] = fmaxf(mr[r], __shfl_xor(mr[r], off, 16));
    }
    if (lrow < 4) pm_s[lq * 4 + lrow][wave] = mr[lrow];
    __syncthreads();  // B: partial maxes ready
    float er[4], sr[4];
    #pragma unroll
    for (int r = 0; r < 4; ++r) {
      int row = lq * 4 + r;
      float gm = fmaxf(fmaxf(pm_s[row][0], pm_s[row][1]),
                       fmaxf(pm_s[row][2], pm_s[row][3]));
      er[r] = __expf(sc[r] - gm);
      sr[r] = er[r];
    }
    #pragma unroll
    for (int off = 8; off; off >>= 1) {
      #pragma unroll
      for (int r = 0; r < 4; ++r) sr[r] += __shfl_xor(sr[r], off, 16);
    }
    if (lrow < 4) ps_s[lq * 4 + lrow][wave] = sr[lrow];
    #pragma unroll
    for (int r = 0; r < 4; ++r)
      kp_s[(lq * 4 + r) * 72 + wave * 16 + lrow] = f2bf(er[r]);
    __syncthreads();  // C: P + partial sums ready
    {
      int col = wave * 16 + lrow;
      f32x4 ov = {0.f, 0.f, 0.f, 0.f};
      #pragma unroll
      for (int kt = 0; kt < 2; ++kt) {
        short8 a = *(const short8*)&kp_s[lrow * 72 + kt * 32 + lq * 8];
        short8 bv = *(const short8*)&vT_s[col * 72 + kt * 32 + lq * 8];
        ov = __builtin_amdgcn_mfma_f32_16x16x32_bf16(a, bv, ov, 0, 0, 0);
      }
      if (col < 56) {
        #pragma unroll
        for (int r = 0; r < 4; ++r) {
          int row = lq * 4 + r;
          float gs = ps_s[row][0] + ps_s[row][1] + ps_s[row][2] + ps_s[row][3];
          float o = ov[r] * (1.f / gs);
          size_t token = ((size_t)(b * 64 + nh * 4 + (row >> 2))) * 64 + (nw * 4 + (row & 3));
          o_bf[token * 224 + h * 56 + col] = f2bf(o);
        }
      }
    }
    __syncthreads();  // D
  }
#undef QKV_EPI
}

// ---------------------------- attn_proj GEMM + bias + residual into hs2
__global__ __launch_bounds__(256, 4) void aproj_kernel(
    const short* __restrict__ o_bf, const short* __restrict__ apF,
    const float* __restrict__ apb, float* __restrict__ hs2) {
  __shared__ alignas(16) short o_s[64 * 232];
  int blk = blockIdx.x;  // 512 x 64 tokens
  int tid = threadIdx.x;
  for (int e = tid; e < 64 * 28; e += 256) {
    int m = e / 28, c = e % 28;
    *(short8*)&o_s[m * 232 + c * 8] =
        *(const short8*)(o_bf + ((size_t)blk * 64 + m) * 224 + c * 8);
  }
  __syncthreads();
  int wave = tid >> 6, lane = tid & 63, lrow = lane & 15, lq = lane >> 4;
  short8 Ao[7];
  #pragma unroll
  for (int kt = 0; kt < 7; ++kt)
    Ao[kt] = *(const short8*)&o_s[(wave * 16 + lrow) * 232 + kt * 32 + lq * 8];
  for (int pr = 0; pr < 7; ++pr) {
    int c0 = pr * 32 + lrow, c1 = c0 + 16;
    f32x4 acc0 = {0.f, 0.f, 0.f, 0.f}, acc1 = {0.f, 0.f, 0.f, 0.f};
    #pragma unroll
    for (int kt = 0; kt < 7; ++kt) {
      short8 b0 = *(const short8*)(apF + (((2 * pr) * 7 + kt) * 64 + lane) * 8);
      short8 b1 = *(const short8*)(apF + (((2 * pr + 1) * 7 + kt) * 64 + lane) * 8);
      acc0 = __builtin_amdgcn_mfma_f32_16x16x32_bf16(Ao[kt], b0, acc0, 0, 0, 0);
      acc1 = __builtin_amdgcn_mfma_f32_16x16x32_bf16(Ao[kt], b1, acc1, 0, 0, 0);
    }
    float bi0 = apb[c0], bi1 = apb[c1];
    #pragma unroll
    for (int r = 0; r < 4; ++r) {
      size_t row = (size_t)blk * 64 + wave * 16 + lq * 4 + r;
      hs2[row * 224 + c0] += acc0[r] + bi0;
      hs2[row * 224 + c1] += acc1[r] + bi1;
    }
  }
}

// ------------- fused LN2 + mlp1 + GELU + mlp2 + residual, 32x32x16 MFMA
// 512 threads, 32 tokens/block; one wave M-tile covers all 32 tokens.
__global__ __launch_bounds__(512, 4) void mlp_kernel(
    const float* __restrict__ hs2, const float* __restrict__ g2,
    const float* __restrict__ b2, const short* __restrict__ m1F,
    const float* __restrict__ b1, const short* __restrict__ m2F,
    const float* __restrict__ b2b, float* __restrict__ out) {
  __shared__ alignas(16) short ln_s[32 * 232];   // 14,848 B
  __shared__ alignas(16) short hid_s[32 * 904];  // 57,856 B => 72,704 B
  int blk = blockIdx.x;  // 1024 x 32 tokens
  int tid = threadIdx.x;
  size_t base = (size_t)blk * 32 * 224;
  // LN2 in registers: 16 lanes per row, one hs2 read
  {
    int row = tid >> 4, l = tid & 15;
    const float* rp = hs2 + base + (size_t)row * 224;
    float v[14];
    float s = 0.f;
    #pragma unroll
    for (int c = 0; c < 14; ++c) { v[c] = rp[l + 16 * c]; s += v[c]; }
    #pragma unroll
    for (int off = 8; off; off >>= 1) s += __shfl_xor(s, off, 16);
    float mean = s * (1.f / 224.f);
    float s2 = 0.f;
    #pragma unroll
    for (int c = 0; c < 14; ++c) { float d = v[c] - mean; s2 = fmaf(d, d, s2); }
    #pragma unroll
    for (int off = 8; off; off >>= 1) s2 += __shfl_xor(s2, off, 16);
    float rs = rsqrtf(s2 * (1.f / 224.f) + 1e-6f);
    #pragma unroll
    for (int c = 0; c < 14; ++c) {
      int cc = l + 16 * c;
      ln_s[row * 232 + cc] = f2bf((v[c] - mean) * rs * g2[cc] + b2[cc]);
    }
  }
  __syncthreads();
  int wave = tid >> 6, lane = tid & 63;
  int nl = lane & 31, half = lane >> 5;
  // GEMM1: 28 N-tiles of 32 over 8 waves (4,4,4,4,3,3,3,3)
  int g1_t0 = (wave < 4) ? wave * 4 : 16 + (wave - 4) * 3;
  int g1_cnt = (wave < 4) ? 4 : 3;
  for (int i = 0; i < g1_cnt; ++i) {
    int nt = g1_t0 + i;
    f32x16 acc = {0.f,0.f,0.f,0.f,0.f,0.f,0.f,0.f,0.f,0.f,0.f,0.f,0.f,0.f,0.f,0.f};
    #pragma unroll
    for (int kt = 0; kt < 14; ++kt) {
      short8 a = *(const short8*)&ln_s[nl * 232 + kt * 16 + half * 8];
      short8 bw = *(const short8*)(m1F + ((size_t)(nt * 14 + kt) * 64 + lane) * 8);
      acc = __builtin_amdgcn_mfma_f32_32x32x16_bf16(a, bw, acc, 0, 0, 0);
    }
    int col = nt * 32 + nl;
    float bi = b1[col];
    #pragma unroll
    for (int r = 0; r < 16; ++r) {
      int row = (r & 3) + 8 * (r >> 2) + 4 * half;
      hid_s[row * 904 + col] = f2bf(gelu_exact(acc[r] + bi));
    }
  }
  __syncthreads();
  // GEMM2: 7 N-tiles of 32 over waves 0..6; 2 interleaved acc chains (kt even/odd)
  if (wave < 7) {
    int nt = wave;
    f32x16 ac0 = {0.f,0.f,0.f,0.f,0.f,0.f,0.f,0.f,0.f,0.f,0.f,0.f,0.f,0.f,0.f,0.f};
    f32x16 ac1 = {0.f,0.f,0.f,0.f,0.f,0.f,0.f,0.f,0.f,0.f,0.f,0.f,0.f,0.f,0.f,0.f};
    #pragma unroll 4
    for (int kt = 0; kt < 56; kt += 2) {
      short8 a0 = *(const short8*)&hid_s[nl * 904 + kt * 16 + half * 8];
      short8 a1 = *(const short8*)&hid_s[nl * 904 + (kt + 1) * 16 + half * 8];
      short8 b0 = *(const short8*)(m2F + ((size_t)(nt * 56 + kt) * 64 + lane) * 8);
      short8 b1 = *(const short8*)(m2F + ((size_t)(nt * 56 + kt + 1) * 64 + lane) * 8);
      ac0 = __builtin_amdgcn_mfma_f32_32x32x16_bf16(a0, b0, ac0, 0, 0, 0);
      ac1 = __builtin_amdgcn_mfma_f32_32x32x16_bf16(a1, b1, ac1, 0, 0, 0);
    }
    int col = nt * 32 + nl;
    float bi = b2b[col];
    #pragma unroll
    for (int r = 0; r < 16; ++r) {
      int row = (r & 3) + 8 * (r >> 2) + 4 * half;
      size_t idx = base + (size_t)row * 224 + col;
      out[idx] = hs2[idx] + ac0[r] + ac1[r] + bi;
    }
  }
}

extern "C" void kernel_launch(void* const* d_in, const int* in_sizes, int n_in,
                              void* d_out, int out_size, void* d_ws, size_t ws_size,
                              hipStream_t stream) {
  const float* x    = (const float*)d_in[0];
  const float* ln1g = (const float*)d_in[1];
  const float* ln1b = (const float*)d_in[2];
  const float* qkvw = (const float*)d_in[3];
  const float* qkvb = (const float*)d_in[4];
  const float* apw  = (const float*)d_in[5];
  const float* apb  = (const float*)d_in[6];
  const float* rpw  = (const float*)d_in[7];
  const float* rpb  = (const float*)d_in[8];
  const float* ln2g = (const float*)d_in[9];
  const float* ln2b = (const float*)d_in[10];
  const float* w1   = (const float*)d_in[11];
  const float* b1   = (const float*)d_in[12];
  const float* w2   = (const float*)d_in[13];
  const float* b2   = (const float*)d_in[14];
  float* out = (float*)d_out;

  short* hs_bf = (short*)d_ws;
  float* hs2   = (float*)((char*)d_ws + 29360128);
  short* o_bf  = (short*)((char*)d_ws + 58720256);
  short* wF    = (short*)((char*)d_ws + 73400320);

  cast_w_kernel<<<1024, 256, 0, stream>>>(qkvw, rpw, apw, w1, w2, wF);
  ln1_kernel<<<32768, 256, 0, stream>>>(x, ln1g, ln1b, hs_bf);
  respool_kernel<<<2048, 256, 0, stream>>>(hs_bf, wF + 90112, rpb, hs2);
  attn_kernel<<<2048, 256, 0, stream>>>(hs_bf, wF, qkvb, o_bf);
  aproj_kernel<<<512, 256, 0, stream>>>(o_bf, wF + 118784, apb, hs2);
  mlp_kernel<<<1024, 512, 0, stream>>>(hs2, ln2g, ln2b, wF + 168960, b1,
                                       wF + 369664, b2, out);
}

// Round 7
// 295.492 us; speedup vs baseline: 1.3008x; 1.0116x over previous
//
#include <hip/hip_runtime.h>
#include <hip/hip_bf16.h>
#include <math.h>

// SAM2 MultiScale Block — round 6: attn LDS union (w_s reused for k/v) -> 7 blk/CU.
// DIM=112(K pad 128), DIM_OUT=224, HEADS=4, HD=56, WS=8, QS=2, MLP=896
//
// ws layout (bytes):
//   hs_bf @ 0          : 131072x112 bf16 = 29,360,128
//   hs2   @ 29,360,128 : 32768x224 f32   = 29,360,128
//   o_bf  @ 58,720,256 : 32768x224 bf16  = 14,680,064
//   wF    @ 73,400,320 : frag-packed bf16 weights (elems):
//     qkvF 704x128 @ +0       rpF 224x128 @ +90112   apF 224x224 @ +118784
//     m1F  896x224 @ +168960  m2F 224x896 @ +369664  (end 570368)
// 16x16 frag order (qkvF/rpF/apF): (n,k) -> tile=(n/16)*KT+(k/32);
//   flat=(tile*64+lane)*8+j, lane=((k%32)/8)*16+(n%16), j=k%8.
// 32x32 frag order (m1F/m2F): (n,k) -> tile=(n/32)*KT16+(k/16);
//   flat=(tile*64+lane)*8+j, lane=((k%16)/8)*32+(n%32), j=k%8.

#define SCALE_A 0.13363062095621219f  // 56^-0.5

typedef __attribute__((ext_vector_type(8))) short short8;
typedef __attribute__((ext_vector_type(4))) float f32x4;
typedef __attribute__((ext_vector_type(16))) float f32x16;

__device__ inline short f2bf(float x) {
  union { float f; unsigned u; } v; v.f = x;
  unsigned r = v.u + 0x7fff + ((v.u >> 16) & 1);
  return (short)(r >> 16);
}
__device__ inline float gelu_exact(float x) {
  return 0.5f * x * (1.f + erff(x * 0.70710678118f));
}

// ------------------------------------------- weight cast to frag order
__global__ void cast_w_kernel(const float* __restrict__ qkv_w,
                              const float* __restrict__ rp_w,
                              const float* __restrict__ ap_w,
                              const float* __restrict__ m1_w,
                              const float* __restrict__ m2_w,
                              short* __restrict__ wF) {
  int tid = blockIdx.x * blockDim.x + threadIdx.x;
  int stride = gridDim.x * blockDim.x;
  // qkvF: permuted cols cp = h*176 + cl; cl: [q 0..55|k 56..111|v 112..167|pad]
  for (int e = tid; e < 90112; e += stride) {
    int j = e & 7, lr = (e >> 3) & 15, lqq = (e >> 7) & 3, tile = e >> 9;
    int kt = tile & 3, nt = tile >> 2;
    int cp = nt * 16 + lr;
    int h = cp / 176, cl = cp % 176;
    int k = kt * 32 + lqq * 8 + j;
    float val = 0.f;
    if (k < 112 && cl < 168) {
      int bcol = (cl < 56) ? (h * 56 + cl)
               : (cl < 112) ? (224 + h * 56 + (cl - 56))
                            : (448 + h * 56 + (cl - 112));
      val = qkv_w[k * 672 + bcol];
    }
    wF[e] = f2bf(val);
  }
  for (int e = tid; e < 28672; e += stride) {  // rpF: N=224, KT=4 (16x16)
    int j = e & 7, lr = (e >> 3) & 15, lqq = (e >> 7) & 3, tile = e >> 9;
    int kt = tile & 3, nt = tile >> 2;
    int n = nt * 16 + lr, k = kt * 32 + lqq * 8 + j;
    wF[90112 + e] = (k < 112) ? f2bf(rp_w[k * 224 + n]) : (short)0;
  }
  for (int e = tid; e < 50176; e += stride) {  // apF: N=224, KT=7 (16x16)
    int j = e & 7, lr = (e >> 3) & 15, lqq = (e >> 7) & 3, tile = e >> 9;
    int kt = tile % 7, nt = tile / 7;
    int n = nt * 16 + lr, k = kt * 32 + lqq * 8 + j;
    wF[118784 + e] = f2bf(ap_w[k * 224 + n]);
  }
  for (int e = tid; e < 200704; e += stride) {  // m1F: N=896/32, K=224/16 (32x32)
    int j = e & 7, lane = (e >> 3) & 63, unit = e >> 9;
    int kt = unit % 14, nt = unit / 14;
    int n = nt * 32 + (lane & 31), k = kt * 16 + (lane >> 5) * 8 + j;
    wF[168960 + e] = f2bf(m1_w[k * 896 + n]);
  }
  for (int e = tid; e < 200704; e += stride) {  // m2F: N=224/32, K=896/16 (32x32)
    int j = e & 7, lane = (e >> 3) & 63, unit = e >> 9;
    int kt = unit % 56, nt = unit / 56;
    int n = nt * 32 + (lane & 31), k = kt * 16 + (lane >> 5) * 8 + j;
    wF[369664 + e] = f2bf(m2_w[k * 224 + n]);
  }
}

// ---------------------------------------------------------------- LN1 -> bf16
__global__ __launch_bounds__(256) void ln1_kernel(
    const float* __restrict__ x, const float* __restrict__ g,
    const float* __restrict__ b, short* __restrict__ hs) {
  int row = blockIdx.x * 4 + (threadIdx.x >> 6);
  int lane = threadIdx.x & 63;
  const float* rp = x + (size_t)row * 112;
  float v0 = rp[lane];
  float v1 = (lane < 48) ? rp[64 + lane] : 0.f;
  float s = v0 + v1;
  #pragma unroll
  for (int off = 32; off; off >>= 1) s += __shfl_down(s, off);
  s = __shfl(s, 0);
  float mean = s * (1.f / 112.f);
  float d0 = v0 - mean;
  float d1 = (lane < 48) ? (v1 - mean) : 0.f;
  float s2 = d0 * d0 + d1 * d1;
  #pragma unroll
  for (int off = 32; off; off >>= 1) s2 += __shfl_down(s2, off);
  s2 = __shfl(s2, 0);
  float rs = rsqrtf(s2 * (1.f / 112.f) + 1e-6f);
  short* op = hs + (size_t)row * 112;
  op[lane] = f2bf(d0 * rs * g[lane] + b[lane]);
  if (lane < 48) op[64 + lane] = f2bf(d1 * rs * g[64 + lane] + b[64 + lane]);
}

// -------------------------------------- res_proj + maxpool2 (MFMA) -> hs2
// LDS 17.4 KB -> 8 blocks/CU (wave-slot limited).
__global__ __launch_bounds__(256, 8) void respool_kernel(
    const short* __restrict__ hs, const short* __restrict__ rpF,
    const float* __restrict__ bias, float* __restrict__ hs2) {
  __shared__ alignas(16) short w_s[64 * 136];
  int blk = blockIdx.x;  // 2048
  int tid = threadIdx.x;
  for (int e = tid; e < 1024; e += 256) {
    int m = e >> 4, c = e & 15;
    short8* dst = (short8*)&w_s[m * 136 + c * 8];
    if (c < 14) {
      int p = m >> 2, r = m & 3;
      int pix = blk * 16 + p;
      int bb = pix >> 12, ii = (pix >> 6) & 63, jj = pix & 63;
      size_t token = ((size_t)(bb * 128 + 2 * ii + (r >> 1))) * 128 + 2 * jj + (r & 1);
      *dst = *(const short8*)(hs + token * 112 + c * 8);
    } else {
      short8 z = {0, 0, 0, 0, 0, 0, 0, 0};
      *dst = z;
    }
  }
  __syncthreads();
  int wave = tid >> 6, lane = tid & 63, lrow = lane & 15, lq = lane >> 4;
  short8 Ar[4];
  #pragma unroll
  for (int kt = 0; kt < 4; ++kt)
    Ar[kt] = *(const short8*)&w_s[(wave * 16 + lrow) * 136 + kt * 32 + lq * 8];
  int p = wave * 4 + lq;
  for (int pr = 0; pr < 7; ++pr) {
    int c0 = pr * 32 + lrow, c1 = c0 + 16;
    f32x4 acc0 = {0.f, 0.f, 0.f, 0.f}, acc1 = {0.f, 0.f, 0.f, 0.f};
    #pragma unroll
    for (int kt = 0; kt < 4; ++kt) {
      short8 b0 = *(const short8*)(rpF + (((2 * pr) * 4 + kt) * 64 + lane) * 8);
      short8 b1 = *(const short8*)(rpF + (((2 * pr + 1) * 4 + kt) * 64 + lane) * 8);
      acc0 = __builtin_amdgcn_mfma_f32_16x16x32_bf16(Ar[kt], b0, acc0, 0, 0, 0);
      acc1 = __builtin_amdgcn_mfma_f32_16x16x32_bf16(Ar[kt], b1, acc1, 0, 0, 0);
    }
    float m0 = fmaxf(fmaxf(acc0[0], acc0[1]), fmaxf(acc0[2], acc0[3])) + bias[c0];
    float m1 = fmaxf(fmaxf(acc1[0], acc1[1]), fmaxf(acc1[2], acc1[3])) + bias[c1];
    hs2[(size_t)(blk * 16 + p) * 224 + c0] = m0;
    hs2[(size_t)(blk * 16 + p) * 224 + c1] = m1;
  }
}

// ------------------- fused windowed attention, LDS union -> 7 blocks/CU
// w_s is dead after the Aq hoist; kp_s/vT_s overlay it (extra barrier after
// hoist). LDS = 18,432 (union) + 2,304 (q) + 512 (pm/ps) = 21,248 B.
__global__ __launch_bounds__(256, 6) void attn_kernel(
    const short* __restrict__ hs, const short* __restrict__ qkvF,
    const float* __restrict__ qkv_b, short* __restrict__ o_bf) {
  __shared__ alignas(16) short u_s[9216];       // 18,432 B union
  __shared__ alignas(16) short q_s[16 * 72];    //  2,304 B
  __shared__ float pm_s[16][4];                 //    256 B
  __shared__ float ps_s[16][4];                 //    256 B
  short* w_s  = u_s;                            // [64*136] staging (hoist only)
  short* kp_s = u_s;                            // [64*72] k; P overlays rows 0..15
  short* vT_s = u_s + 4608;                     // [64*72] hd x keys
  int win = blockIdx.x;                         // 2048
  int nw = win & 15, nh = (win >> 4) & 15, b = win >> 8;
  int tid = threadIdx.x;
  int wave = tid >> 6, lane = tid & 63, lrow = lane & 15, lq = lane >> 4;

  for (int e = tid; e < 1024; e += 256) {
    int m = e >> 4, c = e & 15;
    short8* dst = (short8*)&w_s[m * 136 + c * 8];
    if (c < 14) {
      int p = m >> 2, r = m & 3;
      int tr = (p >> 2) * 2 + (r >> 1), tc = (p & 3) * 2 + (r & 1);
      size_t token = ((size_t)(b * 128 + nh * 8 + tr)) * 128 + (nw * 8 + tc);
      *dst = *(const short8*)(hs + token * 112 + c * 8);
    } else {
      short8 z = {0, 0, 0, 0, 0, 0, 0, 0};
      *dst = z;
    }
  }
  __syncthreads();  // staging done

  short8 Aq[4];
  #pragma unroll
  for (int kt = 0; kt < 4; ++kt)
    Aq[kt] = *(const short8*)&w_s[(wave * 16 + lrow) * 136 + kt * 32 + lq * 8];
  __syncthreads();  // all hoists done; w_s region may now be overwritten

  for (int e = tid; e < 512; e += 256) kp_s[(e >> 3) * 72 + 56 + (e & 7)] = 0;
  if (tid < 128) q_s[(tid >> 3) * 72 + 56 + (tid & 7)] = 0;

#define QKV_EPI(CL, ACC) {                                                \
    int cl_ = (CL);                                                       \
    if (cl_ < 168) {                                                      \
      int bcol_ = (cl_ < 56) ? (h * 56 + cl_)                             \
                : (cl_ < 112) ? (224 + h * 56 + (cl_ - 56))               \
                              : (448 + h * 56 + (cl_ - 112));             \
      float bias_ = qkv_b[bcol_];                                         \
      if (cl_ < 56) {                                                     \
        float mx_ = fmaxf(fmaxf((ACC)[0], (ACC)[1]),                      \
                          fmaxf((ACC)[2], (ACC)[3])) + bias_;             \
        q_s[(wave * 4 + lq) * 72 + cl_] = f2bf(mx_ * SCALE_A);            \
      } else if (cl_ < 112) {                                             \
        _Pragma("unroll")                                                 \
        for (int r_ = 0; r_ < 4; ++r_)                                    \
          kp_s[(wave * 16 + lq * 4 + r_) * 72 + (cl_ - 56)] =             \
              f2bf((ACC)[r_] + bias_);                                    \
      } else {                                                            \
        _Pragma("unroll")                                                 \
        for (int r_ = 0; r_ < 4; ++r_)                                    \
          vT_s[(cl_ - 112) * 72 + wave * 16 + lq * 4 + r_] =              \
              f2bf((ACC)[r_] + bias_);                                    \
      }                                                                   \
    }                                                                     \
  }

  for (int h = 0; h < 4; ++h) {
    if (h && tid < 128) kp_s[(tid >> 3) * 72 + 56 + (tid & 7)] = 0;  // P-clobbered pad
    for (int pr = 0; pr < 5; ++pr) {
      int t0 = 2 * pr, t1 = t0 + 1;
      int cl0 = t0 * 16 + lrow, cl1 = cl0 + 16;
      f32x4 acc0 = {0.f, 0.f, 0.f, 0.f}, acc1 = {0.f, 0.f, 0.f, 0.f};
      #pragma unroll
      for (int kt = 0; kt < 4; ++kt) {
        short8 b0 = *(const short8*)(qkvF + (((h * 11 + t0) * 4 + kt) * 64 + lane) * 8);
        short8 b1 = *(const short8*)(qkvF + (((h * 11 + t1) * 4 + kt) * 64 + lane) * 8);
        acc0 = __builtin_amdgcn_mfma_f32_16x16x32_bf16(Aq[kt], b0, acc0, 0, 0, 0);
        acc1 = __builtin_amdgcn_mfma_f32_16x16x32_bf16(Aq[kt], b1, acc1, 0, 0, 0);
      }
      QKV_EPI(cl0, acc0);
      QKV_EPI(cl1, acc1);
    }
    {
      int cl = 160 + lrow;
      f32x4 acc = {0.f, 0.f, 0.f, 0.f};
      #pragma unroll
      for (int kt = 0; kt < 4; ++kt) {
        short8 bf = *(const short8*)(qkvF + (((h * 11 + 10) * 4 + kt) * 64 + lane) * 8);
        acc = __builtin_amdgcn_mfma_f32_16x16x32_bf16(Aq[kt], bf, acc, 0, 0, 0);
      }
      QKV_EPI(cl, acc);
    }
    __syncthreads();  // A: q/k/v ready
    f32x4 sc = {0.f, 0.f, 0.f, 0.f};
    #pragma unroll
    for (int kt = 0; kt < 2; ++kt) {
      short8 a = *(const short8*)&q_s[lrow * 72 + kt * 32 + lq * 8];
      short8 bk = *(const short8*)&kp_s[(wave * 16 + lrow) * 72 + kt * 32 + lq * 8];
      sc = __builtin_amdgcn_mfma_f32_16x16x32_bf16(a, bk, sc, 0, 0, 0);
    }
    float mr[4] = {sc[0], sc[1], sc[2], sc[3]};
    #pragma unroll
    for (int off = 8; off; off >>= 1) {
      #pragma unroll
      for (int r = 0; r < 4; ++r) mr[r] = fmaxf(mr[r], __shfl_xor(mr[r], off, 16));
    }
    if (lrow < 4) pm_s[lq * 4 + lrow][wave] = mr[lrow];
    __syncthreads();  // B: partial maxes ready
    float er[4], sr[4];
    #pragma unroll
    for (int r = 0; r < 4; ++r) {
      int row = lq * 4 + r;
      float gm = fmaxf(fmaxf(pm_s[row][0], pm_s[row][1]),
                       fmaxf(pm_s[row][2], pm_s[row][3]));
      er[r] = __expf(sc[r] - gm);
      sr[r] = er[r];
    }
    #pragma unroll
    for (int off = 8; off; off >>= 1) {
      #pragma unroll
      for (int r = 0; r < 4; ++r) sr[r] += __shfl_xor(sr[r], off, 16);
    }
    if (lrow < 4) ps_s[lq * 4 + lrow][wave] = sr[lrow];
    #pragma unroll
    for (int r = 0; r < 4; ++r)
      kp_s[(lq * 4 + r) * 72 + wave * 16 + lrow] = f2bf(er[r]);
    __syncthreads();  // C: P + partial sums ready
    {
      int col = wave * 16 + lrow;
      f32x4 ov = {0.f, 0.f, 0.f, 0.f};
      #pragma unroll
      for (int kt = 0; kt < 2; ++kt) {
        short8 a = *(const short8*)&kp_s[lrow * 72 + kt * 32 + lq * 8];
        short8 bv = *(const short8*)&vT_s[col * 72 + kt * 32 + lq * 8];
        ov = __builtin_amdgcn_mfma_f32_16x16x32_bf16(a, bv, ov, 0, 0, 0);
      }
      if (col < 56) {
        #pragma unroll
        for (int r = 0; r < 4; ++r) {
          int row = lq * 4 + r;
          float gs = ps_s[row][0] + ps_s[row][1] + ps_s[row][2] + ps_s[row][3];
          float o = ov[r] * (1.f / gs);
          size_t token = ((size_t)(b * 64 + nh * 4 + (row >> 2))) * 64 + (nw * 4 + (row & 3));
          o_bf[token * 224 + h * 56 + col] = f2bf(o);
        }
      }
    }
    __syncthreads();  // D
  }
#undef QKV_EPI
}

// ---------------------------- attn_proj GEMM + bias + residual into hs2
// LDS 29.7 KB -> 5 blocks/CU.
__global__ __launch_bounds__(256, 5) void aproj_kernel(
    const short* __restrict__ o_bf, const short* __restrict__ apF,
    const float* __restrict__ apb, float* __restrict__ hs2) {
  __shared__ alignas(16) short o_s[64 * 232];
  int blk = blockIdx.x;  // 512 x 64 tokens
  int tid = threadIdx.x;
  for (int e = tid; e < 64 * 28; e += 256) {
    int m = e / 28, c = e % 28;
    *(short8*)&o_s[m * 232 + c * 8] =
        *(const short8*)(o_bf + ((size_t)blk * 64 + m) * 224 + c * 8);
  }
  __syncthreads();
  int wave = tid >> 6, lane = tid & 63, lrow = lane & 15, lq = lane >> 4;
  short8 Ao[7];
  #pragma unroll
  for (int kt = 0; kt < 7; ++kt)
    Ao[kt] = *(const short8*)&o_s[(wave * 16 + lrow) * 232 + kt * 32 + lq * 8];
  for (int pr = 0; pr < 7; ++pr) {
    int c0 = pr * 32 + lrow, c1 = c0 + 16;
    f32x4 acc0 = {0.f, 0.f, 0.f, 0.f}, acc1 = {0.f, 0.f, 0.f, 0.f};
    #pragma unroll
    for (int kt = 0; kt < 7; ++kt) {
      short8 b0 = *(const short8*)(apF + (((2 * pr) * 7 + kt) * 64 + lane) * 8);
      short8 b1 = *(const short8*)(apF + (((2 * pr + 1) * 7 + kt) * 64 + lane) * 8);
      acc0 = __builtin_amdgcn_mfma_f32_16x16x32_bf16(Ao[kt], b0, acc0, 0, 0, 0);
      acc1 = __builtin_amdgcn_mfma_f32_16x16x32_bf16(Ao[kt], b1, acc1, 0, 0, 0);
    }
    float bi0 = apb[c0], bi1 = apb[c1];
    #pragma unroll
    for (int r = 0; r < 4; ++r) {
      size_t row = (size_t)blk * 64 + wave * 16 + lq * 4 + r;
      hs2[row * 224 + c0] += acc0[r] + bi0;
      hs2[row * 224 + c1] += acc1[r] + bi1;
    }
  }
}

// ------------- fused LN2 + mlp1 + GELU + mlp2 + residual, 32x32x16 MFMA
__global__ __launch_bounds__(512, 4) void mlp_kernel(
    const float* __restrict__ hs2, const float* __restrict__ g2,
    const float* __restrict__ b2, const short* __restrict__ m1F,
    const float* __restrict__ b1, const short* __restrict__ m2F,
    const float* __restrict__ b2b, float* __restrict__ out) {
  __shared__ alignas(16) short ln_s[32 * 232];   // 14,848 B
  __shared__ alignas(16) short hid_s[32 * 904];  // 57,856 B => 72,704 B
  int blk = blockIdx.x;  // 1024 x 32 tokens
  int tid = threadIdx.x;
  size_t base = (size_t)blk * 32 * 224;
  {
    int row = tid >> 4, l = tid & 15;
    const float* rp = hs2 + base + (size_t)row * 224;
    float v[14];
    float s = 0.f;
    #pragma unroll
    for (int c = 0; c < 14; ++c) { v[c] = rp[l + 16 * c]; s += v[c]; }
    #pragma unroll
    for (int off = 8; off; off >>= 1) s += __shfl_xor(s, off, 16);
    float mean = s * (1.f / 224.f);
    float s2 = 0.f;
    #pragma unroll
    for (int c = 0; c < 14; ++c) { float d = v[c] - mean; s2 = fmaf(d, d, s2); }
    #pragma unroll
    for (int off = 8; off; off >>= 1) s2 += __shfl_xor(s2, off, 16);
    float rs = rsqrtf(s2 * (1.f / 224.f) + 1e-6f);
    #pragma unroll
    for (int c = 0; c < 14; ++c) {
      int cc = l + 16 * c;
      ln_s[row * 232 + cc] = f2bf((v[c] - mean) * rs * g2[cc] + b2[cc]);
    }
  }
  __syncthreads();
  int wave = tid >> 6, lane = tid & 63;
  int nl = lane & 31, half = lane >> 5;
  int g1_t0 = (wave < 4) ? wave * 4 : 16 + (wave - 4) * 3;
  int g1_cnt = (wave < 4) ? 4 : 3;
  for (int i = 0; i < g1_cnt; ++i) {
    int nt = g1_t0 + i;
    f32x16 acc = {0.f,0.f,0.f,0.f,0.f,0.f,0.f,0.f,0.f,0.f,0.f,0.f,0.f,0.f,0.f,0.f};
    #pragma unroll
    for (int kt = 0; kt < 14; ++kt) {
      short8 a = *(const short8*)&ln_s[nl * 232 + kt * 16 + half * 8];
      short8 bw = *(const short8*)(m1F + ((size_t)(nt * 14 + kt) * 64 + lane) * 8);
      acc = __builtin_amdgcn_mfma_f32_32x32x16_bf16(a, bw, acc, 0, 0, 0);
    }
    int col = nt * 32 + nl;
    float bi = b1[col];
    #pragma unroll
    for (int r = 0; r < 16; ++r) {
      int row = (r & 3) + 8 * (r >> 2) + 4 * half;
      hid_s[row * 904 + col] = f2bf(gelu_exact(acc[r] + bi));
    }
  }
  __syncthreads();
  if (wave < 7) {
    int nt = wave;
    f32x16 ac0 = {0.f,0.f,0.f,0.f,0.f,0.f,0.f,0.f,0.f,0.f,0.f,0.f,0.f,0.f,0.f,0.f};
    f32x16 ac1 = {0.f,0.f,0.f,0.f,0.f,0.f,0.f,0.f,0.f,0.f,0.f,0.f,0.f,0.f,0.f,0.f};
    #pragma unroll 4
    for (int kt = 0; kt < 56; kt += 2) {
      short8 a0 = *(const short8*)&hid_s[nl * 904 + kt * 16 + half * 8];
      short8 a1 = *(const short8*)&hid_s[nl * 904 + (kt + 1) * 16 + half * 8];
      short8 b0 = *(const short8*)(m2F + ((size_t)(nt * 56 + kt) * 64 + lane) * 8);
      short8 b1 = *(const short8*)(m2F + ((size_t)(nt * 56 + kt + 1) * 64 + lane) * 8);
      ac0 = __builtin_amdgcn_mfma_f32_32x32x16_bf16(a0, b0, ac0, 0, 0, 0);
      ac1 = __builtin_amdgcn_mfma_f32_32x32x16_bf16(a1, b1, ac1, 0, 0, 0);
    }
    int col = nt * 32 + nl;
    float bi = b2b[col];
    #pragma unroll
    for (int r = 0; r < 16; ++r) {
      int row = (r & 3) + 8 * (r >> 2) + 4 * half;
      size_t idx = base + (size_t)row * 224 + col;
      out[idx] = hs2[idx] + ac0[r] + ac1[r] + bi;
    }
  }
}

extern "C" void kernel_launch(void* const* d_in, const int* in_sizes, int n_in,
                              void* d_out, int out_size, void* d_ws, size_t ws_size,
                              hipStream_t stream) {
  const float* x    = (const float*)d_in[0];
  const float* ln1g = (const float*)d_in[1];
  const float* ln1b = (const float*)d_in[2];
  const float* qkvw = (const float*)d_in[3];
  const float* qkvb = (const float*)d_in[4];
  const float* apw  = (const float*)d_in[5];
  const float* apb  = (const float*)d_in[6];
  const float* rpw  = (const float*)d_in[7];
  const float* rpb  = (const float*)d_in[8];
  const float* ln2g = (const float*)d_in[9];
  const float* ln2b = (const float*)d_in[10];
  const float* w1   = (const float*)d_in[11];
  const float* b1   = (const float*)d_in[12];
  const float* w2   = (const float*)d_in[13];
  const float* b2   = (const float*)d_in[14];
  float* out = (float*)d_out;

  short* hs_bf = (short*)d_ws;
  float* hs2   = (float*)((char*)d_ws + 29360128);
  short* o_bf  = (short*)((char*)d_ws + 58720256);
  short* wF    = (short*)((char*)d_ws + 73400320);

  cast_w_kernel<<<1024, 256, 0, stream>>>(qkvw, rpw, apw, w1, w2, wF);
  ln1_kernel<<<32768, 256, 0, stream>>>(x, ln1g, ln1b, hs_bf);
  respool_kernel<<<2048, 256, 0, stream>>>(hs_bf, wF + 90112, rpb, hs2);
  attn_kernel<<<2048, 256, 0, stream>>>(hs_bf, wF, qkvb, o_bf);
  aproj_kernel<<<512, 256, 0, stream>>>(o_bf, wF + 118784, apb, hs2);
  mlp_kernel<<<1024, 512, 0, stream>>>(hs2, ln2g, ln2b, wF + 168960, b1,
                                       wF + 369664, b2, out);
}

// Round 8
// 282.270 us; speedup vs baseline: 1.3617x; 1.0468x over previous
//
#include <hip/hip_runtime.h>
#include <hip/hip_bf16.h>
#include <math.h>

// SAM2 MultiScale Block — round 7: attn qkv N-ownership (L2 /4) + wave-local
// softmax (barriers 18 -> 10). Other kernels identical to R6.
// DIM=112(K pad 128), DIM_OUT=224, HEADS=4, HD=56, WS=8, QS=2, MLP=896
//
// ws layout (bytes):
//   hs_bf @ 0          : 131072x112 bf16 = 29,360,128
//   hs2   @ 29,360,128 : 32768x224 f32   = 29,360,128
//   o_bf  @ 58,720,256 : 32768x224 bf16  = 14,680,064
//   wF    @ 73,400,320 : frag-packed bf16 weights (elems):
//     qkvF 704x128 @ +0       rpF 224x128 @ +90112   apF 224x224 @ +118784
//     m1F  896x224 @ +168960  m2F 224x896 @ +369664  (end 570368)
// 16x16 frag order (qkvF/rpF/apF): (n,k) -> tile=(n/16)*KT+(k/32);
//   flat=(tile*64+lane)*8+j, lane=((k%32)/8)*16+(n%16), j=k%8.
// 32x32 frag order (m1F/m2F): (n,k) -> tile=(n/32)*KT16+(k/16);
//   flat=(tile*64+lane)*8+j, lane=((k%16)/8)*32+(n%32), j=k%8.

#define SCALE_A 0.13363062095621219f  // 56^-0.5

typedef __attribute__((ext_vector_type(8))) short short8;
typedef __attribute__((ext_vector_type(4))) short short4v;
typedef __attribute__((ext_vector_type(4))) float f32x4;
typedef __attribute__((ext_vector_type(16))) float f32x16;

__device__ inline short f2bf(float x) {
  union { float f; unsigned u; } v; v.f = x;
  unsigned r = v.u + 0x7fff + ((v.u >> 16) & 1);
  return (short)(r >> 16);
}
__device__ inline float gelu_exact(float x) {
  return 0.5f * x * (1.f + erff(x * 0.70710678118f));
}

// ------------------------------------------- weight cast to frag order
__global__ void cast_w_kernel(const float* __restrict__ qkv_w,
                              const float* __restrict__ rp_w,
                              const float* __restrict__ ap_w,
                              const float* __restrict__ m1_w,
                              const float* __restrict__ m2_w,
                              short* __restrict__ wF) {
  int tid = blockIdx.x * blockDim.x + threadIdx.x;
  int stride = gridDim.x * blockDim.x;
  // qkvF: permuted cols cp = h*176 + cl; cl: [q 0..55|k 56..111|v 112..167|pad]
  for (int e = tid; e < 90112; e += stride) {
    int j = e & 7, lr = (e >> 3) & 15, lqq = (e >> 7) & 3, tile = e >> 9;
    int kt = tile & 3, nt = tile >> 2;
    int cp = nt * 16 + lr;
    int h = cp / 176, cl = cp % 176;
    int k = kt * 32 + lqq * 8 + j;
    float val = 0.f;
    if (k < 112 && cl < 168) {
      int bcol = (cl < 56) ? (h * 56 + cl)
               : (cl < 112) ? (224 + h * 56 + (cl - 56))
                            : (448 + h * 56 + (cl - 112));
      val = qkv_w[k * 672 + bcol];
    }
    wF[e] = f2bf(val);
  }
  for (int e = tid; e < 28672; e += stride) {  // rpF: N=224, KT=4 (16x16)
    int j = e & 7, lr = (e >> 3) & 15, lqq = (e >> 7) & 3, tile = e >> 9;
    int kt = tile & 3, nt = tile >> 2;
    int n = nt * 16 + lr, k = kt * 32 + lqq * 8 + j;
    wF[90112 + e] = (k < 112) ? f2bf(rp_w[k * 224 + n]) : (short)0;
  }
  for (int e = tid; e < 50176; e += stride) {  // apF: N=224, KT=7 (16x16)
    int j = e & 7, lr = (e >> 3) & 15, lqq = (e >> 7) & 3, tile = e >> 9;
    int kt = tile % 7, nt = tile / 7;
    int n = nt * 16 + lr, k = kt * 32 + lqq * 8 + j;
    wF[118784 + e] = f2bf(ap_w[k * 224 + n]);
  }
  for (int e = tid; e < 200704; e += stride) {  // m1F: N=896/32, K=224/16 (32x32)
    int j = e & 7, lane = (e >> 3) & 63, unit = e >> 9;
    int kt = unit % 14, nt = unit / 14;
    int n = nt * 32 + (lane & 31), k = kt * 16 + (lane >> 5) * 8 + j;
    wF[168960 + e] = f2bf(m1_w[k * 896 + n]);
  }
  for (int e = tid; e < 200704; e += stride) {  // m2F: N=224/32, K=896/16 (32x32)
    int j = e & 7, lane = (e >> 3) & 63, unit = e >> 9;
    int kt = unit % 56, nt = unit / 56;
    int n = nt * 32 + (lane & 31), k = kt * 16 + (lane >> 5) * 8 + j;
    wF[369664 + e] = f2bf(m2_w[k * 224 + n]);
  }
}

// ---------------------------------------------------------------- LN1 -> bf16
__global__ __launch_bounds__(256) void ln1_kernel(
    const float* __restrict__ x, const float* __restrict__ g,
    const float* __restrict__ b, short* __restrict__ hs) {
  int row = blockIdx.x * 4 + (threadIdx.x >> 6);
  int lane = threadIdx.x & 63;
  const float* rp = x + (size_t)row * 112;
  float v0 = rp[lane];
  float v1 = (lane < 48) ? rp[64 + lane] : 0.f;
  float s = v0 + v1;
  #pragma unroll
  for (int off = 32; off; off >>= 1) s += __shfl_down(s, off);
  s = __shfl(s, 0);
  float mean = s * (1.f / 112.f);
  float d0 = v0 - mean;
  float d1 = (lane < 48) ? (v1 - mean) : 0.f;
  float s2 = d0 * d0 + d1 * d1;
  #pragma unroll
  for (int off = 32; off; off >>= 1) s2 += __shfl_down(s2, off);
  s2 = __shfl(s2, 0);
  float rs = rsqrtf(s2 * (1.f / 112.f) + 1e-6f);
  short* op = hs + (size_t)row * 112;
  op[lane] = f2bf(d0 * rs * g[lane] + b[lane]);
  if (lane < 48) op[64 + lane] = f2bf(d1 * rs * g[64 + lane] + b[64 + lane]);
}

// -------------------------------------- res_proj + maxpool2 (MFMA) -> hs2
__global__ __launch_bounds__(256, 8) void respool_kernel(
    const short* __restrict__ hs, const short* __restrict__ rpF,
    const float* __restrict__ bias, float* __restrict__ hs2) {
  __shared__ alignas(16) short w_s[64 * 136];
  int blk = blockIdx.x;  // 2048
  int tid = threadIdx.x;
  for (int e = tid; e < 1024; e += 256) {
    int m = e >> 4, c = e & 15;
    short8* dst = (short8*)&w_s[m * 136 + c * 8];
    if (c < 14) {
      int p = m >> 2, r = m & 3;
      int pix = blk * 16 + p;
      int bb = pix >> 12, ii = (pix >> 6) & 63, jj = pix & 63;
      size_t token = ((size_t)(bb * 128 + 2 * ii + (r >> 1))) * 128 + 2 * jj + (r & 1);
      *dst = *(const short8*)(hs + token * 112 + c * 8);
    } else {
      short8 z = {0, 0, 0, 0, 0, 0, 0, 0};
      *dst = z;
    }
  }
  __syncthreads();
  int wave = tid >> 6, lane = tid & 63, lrow = lane & 15, lq = lane >> 4;
  short8 Ar[4];
  #pragma unroll
  for (int kt = 0; kt < 4; ++kt)
    Ar[kt] = *(const short8*)&w_s[(wave * 16 + lrow) * 136 + kt * 32 + lq * 8];
  int p = wave * 4 + lq;
  for (int pr = 0; pr < 7; ++pr) {
    int c0 = pr * 32 + lrow, c1 = c0 + 16;
    f32x4 acc0 = {0.f, 0.f, 0.f, 0.f}, acc1 = {0.f, 0.f, 0.f, 0.f};
    #pragma unroll
    for (int kt = 0; kt < 4; ++kt) {
      short8 b0 = *(const short8*)(rpF + (((2 * pr) * 4 + kt) * 64 + lane) * 8);
      short8 b1 = *(const short8*)(rpF + (((2 * pr + 1) * 4 + kt) * 64 + lane) * 8);
      acc0 = __builtin_amdgcn_mfma_f32_16x16x32_bf16(Ar[kt], b0, acc0, 0, 0, 0);
      acc1 = __builtin_amdgcn_mfma_f32_16x16x32_bf16(Ar[kt], b1, acc1, 0, 0, 0);
    }
    float m0 = fmaxf(fmaxf(acc0[0], acc0[1]), fmaxf(acc0[2], acc0[3])) + bias[c0];
    float m1 = fmaxf(fmaxf(acc1[0], acc1[1]), fmaxf(acc1[2], acc1[3])) + bias[c1];
    hs2[(size_t)(blk * 16 + p) * 224 + c0] = m0;
    hs2[(size_t)(blk * 16 + p) * 224 + c1] = m1;
  }
}

// ------------------- fused windowed attention, round 7
// qkv: waves own N-tiles (B loaded once per block), all 4 M-tiles via hoisted
// A-frags (64 VGPR). Softmax fully wave-local (full 16x64 scores per wave,
// 16-lane shuffles, private P region, no pm/ps). 2 barriers per head.
// LDS: union(w_s 17408B | k_s 9216B + vT_s 9216B) = 18432 + q_s 2304
//      + p_s 9216 = 29,952 B.
__global__ __launch_bounds__(256, 4) void attn_kernel(
    const short* __restrict__ hs, const short* __restrict__ qkvF,
    const float* __restrict__ qkv_b, short* __restrict__ o_bf) {
  __shared__ alignas(16) short u_s[9216];       // 18,432 B union
  __shared__ alignas(16) short q_s[16 * 72];    //  2,304 B (pooled q * scale)
  __shared__ alignas(16) short p_s[4 * 16 * 72];//  9,216 B private P per wave
  short* w_s  = u_s;                            // [64*136] staging (hoist only)
  short* k_s  = u_s;                            // [64*72] keys x hd (pad 56..63=0)
  short* vT_s = u_s + 4608;                     // [64*72] hd x keys
  int win = blockIdx.x;                         // 2048
  int nw = win & 15, nh = (win >> 4) & 15, b = win >> 8;
  int tid = threadIdx.x;
  int wave = tid >> 6, lane = tid & 63, lrow = lane & 15, lq = lane >> 4;

  for (int e = tid; e < 1024; e += 256) {
    int m = e >> 4, c = e & 15;
    short8* dst = (short8*)&w_s[m * 136 + c * 8];
    if (c < 14) {
      int p = m >> 2, r = m & 3;
      int tr = (p >> 2) * 2 + (r >> 1), tc = (p & 3) * 2 + (r & 1);
      size_t token = ((size_t)(b * 128 + nh * 8 + tr)) * 128 + (nw * 8 + tc);
      *dst = *(const short8*)(hs + token * 112 + c * 8);
    } else {
      short8 z = {0, 0, 0, 0, 0, 0, 0, 0};
      *dst = z;
    }
  }
  __syncthreads();  // staging done

  // hoist A-frags for ALL 4 M-tiles (shared across all N-tiles): 64 VGPR
  short8 Aw[4][4];
  #pragma unroll
  for (int mt = 0; mt < 4; ++mt)
    #pragma unroll
    for (int kt = 0; kt < 4; ++kt)
      Aw[mt][kt] = *(const short8*)&w_s[(mt * 16 + lrow) * 136 + kt * 32 + lq * 8];
  __syncthreads();  // hoists done; w_s region may be overwritten

  // zero pads ONCE (P is private now; nothing clobbers these)
  for (int e = tid; e < 512; e += 256) k_s[(e >> 3) * 72 + 56 + (e & 7)] = 0;
  if (tid < 128) q_s[(tid >> 3) * 72 + 56 + (tid & 7)] = 0;

  // N-tile ownership: 11 tiles -> waves {3,3,3,2}
  int nt0 = (wave < 3) ? wave * 3 : 9;
  int ncnt = (wave < 3) ? 3 : 2;
  short* p_w = p_s + wave * 1152;  // private 16x72

  for (int h = 0; h < 4; ++h) {
    if (h) __syncthreads();  // all cores done reading k/v/q before overwrite
    // ---- qkv: own N-tiles, all 4 M-tiles (B loaded once per block)
    for (int i = 0; i < ncnt; ++i) {
      int t = nt0 + i;
      int cl = t * 16 + lrow;
      f32x4 ac[4] = {{0.f,0.f,0.f,0.f},{0.f,0.f,0.f,0.f},
                     {0.f,0.f,0.f,0.f},{0.f,0.f,0.f,0.f}};
      #pragma unroll
      for (int kt = 0; kt < 4; ++kt) {
        short8 bw = *(const short8*)(qkvF + (((h * 11 + t) * 4 + kt) * 64 + lane) * 8);
        #pragma unroll
        for (int mt = 0; mt < 4; ++mt)
          ac[mt] = __builtin_amdgcn_mfma_f32_16x16x32_bf16(Aw[mt][kt], bw, ac[mt], 0, 0, 0);
      }
      if (cl < 56) {
        float bias = qkv_b[h * 56 + cl];
        #pragma unroll
        for (int mt = 0; mt < 4; ++mt) {
          float mx = fmaxf(fmaxf(ac[mt][0], ac[mt][1]),
                           fmaxf(ac[mt][2], ac[mt][3])) + bias;
          q_s[(mt * 4 + lq) * 72 + cl] = f2bf(mx * SCALE_A);
        }
      } else if (cl < 112) {
        float bias = qkv_b[224 + h * 56 + (cl - 56)];
        #pragma unroll
        for (int mt = 0; mt < 4; ++mt)
          #pragma unroll
          for (int r = 0; r < 4; ++r)
            k_s[(mt * 16 + lq * 4 + r) * 72 + (cl - 56)] = f2bf(ac[mt][r] + bias);
      } else if (cl < 168) {
        float bias = qkv_b[448 + h * 56 + (cl - 112)];
        #pragma unroll
        for (int mt = 0; mt < 4; ++mt) {
          short4v pk = {f2bf(ac[mt][0] + bias), f2bf(ac[mt][1] + bias),
                        f2bf(ac[mt][2] + bias), f2bf(ac[mt][3] + bias)};
          *(short4v*)&vT_s[(cl - 112) * 72 + mt * 16 + lq * 4] = pk;
        }
      }
    }
    __syncthreads();  // k/v/q ready

    // ---- core: fully wave-local
    // full 16x64 scores: 4 N-tiles x 2 kt
    short8 aq[2];
    #pragma unroll
    for (int kt = 0; kt < 2; ++kt)
      aq[kt] = *(const short8*)&q_s[lrow * 72 + kt * 32 + lq * 8];
    f32x4 sc[4];
    #pragma unroll
    for (int t = 0; t < 4; ++t) {
      sc[t][0] = sc[t][1] = sc[t][2] = sc[t][3] = 0.f;
      #pragma unroll
      for (int kt = 0; kt < 2; ++kt) {
        short8 bk = *(const short8*)&k_s[(t * 16 + lrow) * 72 + kt * 32 + lq * 8];
        sc[t] = __builtin_amdgcn_mfma_f32_16x16x32_bf16(aq[kt], bk, sc[t], 0, 0, 0);
      }
    }
    // softmax rows lq*4+r: reduce over t (local) and lrow (16-lane shuffles)
    float mr[4], sr[4];
    #pragma unroll
    for (int r = 0; r < 4; ++r)
      mr[r] = fmaxf(fmaxf(sc[0][r], sc[1][r]), fmaxf(sc[2][r], sc[3][r]));
    #pragma unroll
    for (int off = 8; off; off >>= 1)
      #pragma unroll
      for (int r = 0; r < 4; ++r) mr[r] = fmaxf(mr[r], __shfl_xor(mr[r], off, 16));
    #pragma unroll
    for (int r = 0; r < 4; ++r) {
      #pragma unroll
      for (int t = 0; t < 4; ++t) sc[t][r] = __expf(sc[t][r] - mr[r]);
      sr[r] = sc[0][r] + sc[1][r] + sc[2][r] + sc[3][r];
    }
    #pragma unroll
    for (int off = 8; off; off >>= 1)
      #pragma unroll
      for (int r = 0; r < 4; ++r) sr[r] += __shfl_xor(sr[r], off, 16);
    #pragma unroll
    for (int r = 0; r < 4; ++r) sr[r] = 1.f / sr[r];
    // normalized P -> private LDS (no barrier: same-wave write->read)
    #pragma unroll
    for (int t = 0; t < 4; ++t)
      #pragma unroll
      for (int r = 0; r < 4; ++r)
        p_w[(lq * 4 + r) * 72 + t * 16 + lrow] = f2bf(sc[t][r] * sr[r]);
    // PV: wave owns out cols [wave*16, +16)
    {
      int col = wave * 16 + lrow;
      f32x4 ov = {0.f, 0.f, 0.f, 0.f};
      #pragma unroll
      for (int kt = 0; kt < 2; ++kt) {
        short8 a = *(const short8*)&p_w[lrow * 72 + kt * 32 + lq * 8];
        short8 bv = *(const short8*)&vT_s[col * 72 + kt * 32 + lq * 8];
        ov = __builtin_amdgcn_mfma_f32_16x16x32_bf16(a, bv, ov, 0, 0, 0);
      }
      if (col < 56) {
        #pragma unroll
        for (int r = 0; r < 4; ++r) {
          int row = lq * 4 + r;
          size_t token = ((size_t)(b * 64 + nh * 4 + (row >> 2))) * 64 + (nw * 4 + (row & 3));
          o_bf[token * 224 + h * 56 + col] = f2bf(ov[r]);
        }
      }
    }
  }
}

// ---------------------------- attn_proj GEMM + bias + residual into hs2
__global__ __launch_bounds__(256, 5) void aproj_kernel(
    const short* __restrict__ o_bf, const short* __restrict__ apF,
    const float* __restrict__ apb, float* __restrict__ hs2) {
  __shared__ alignas(16) short o_s[64 * 232];
  int blk = blockIdx.x;  // 512 x 64 tokens
  int tid = threadIdx.x;
  for (int e = tid; e < 64 * 28; e += 256) {
    int m = e / 28, c = e % 28;
    *(short8*)&o_s[m * 232 + c * 8] =
        *(const short8*)(o_bf + ((size_t)blk * 64 + m) * 224 + c * 8);
  }
  __syncthreads();
  int wave = tid >> 6, lane = tid & 63, lrow = lane & 15, lq = lane >> 4;
  short8 Ao[7];
  #pragma unroll
  for (int kt = 0; kt < 7; ++kt)
    Ao[kt] = *(const short8*)&o_s[(wave * 16 + lrow) * 232 + kt * 32 + lq * 8];
  for (int pr = 0; pr < 7; ++pr) {
    int c0 = pr * 32 + lrow, c1 = c0 + 16;
    f32x4 acc0 = {0.f, 0.f, 0.f, 0.f}, acc1 = {0.f, 0.f, 0.f, 0.f};
    #pragma unroll
    for (int kt = 0; kt < 7; ++kt) {
      short8 b0 = *(const short8*)(apF + (((2 * pr) * 7 + kt) * 64 + lane) * 8);
      short8 b1 = *(const short8*)(apF + (((2 * pr + 1) * 7 + kt) * 64 + lane) * 8);
      acc0 = __builtin_amdgcn_mfma_f32_16x16x32_bf16(Ao[kt], b0, acc0, 0, 0, 0);
      acc1 = __builtin_amdgcn_mfma_f32_16x16x32_bf16(Ao[kt], b1, acc1, 0, 0, 0);
    }
    float bi0 = apb[c0], bi1 = apb[c1];
    #pragma unroll
    for (int r = 0; r < 4; ++r) {
      size_t row = (size_t)blk * 64 + wave * 16 + lq * 4 + r;
      hs2[row * 224 + c0] += acc0[r] + bi0;
      hs2[row * 224 + c1] += acc1[r] + bi1;
    }
  }
}

// ------------- fused LN2 + mlp1 + GELU + mlp2 + residual, 32x32x16 MFMA
__global__ __launch_bounds__(512, 4) void mlp_kernel(
    const float* __restrict__ hs2, const float* __restrict__ g2,
    const float* __restrict__ b2, const short* __restrict__ m1F,
    const float* __restrict__ b1, const short* __restrict__ m2F,
    const float* __restrict__ b2b, float* __restrict__ out) {
  __shared__ alignas(16) short ln_s[32 * 232];   // 14,848 B
  __shared__ alignas(16) short hid_s[32 * 904];  // 57,856 B => 72,704 B
  int blk = blockIdx.x;  // 1024 x 32 tokens
  int tid = threadIdx.x;
  size_t base = (size_t)blk * 32 * 224;
  {
    int row = tid >> 4, l = tid & 15;
    const float* rp = hs2 + base + (size_t)row * 224;
    float v[14];
    float s = 0.f;
    #pragma unroll
    for (int c = 0; c < 14; ++c) { v[c] = rp[l + 16 * c]; s += v[c]; }
    #pragma unroll
    for (int off = 8; off; off >>= 1) s += __shfl_xor(s, off, 16);
    float mean = s * (1.f / 224.f);
    float s2 = 0.f;
    #pragma unroll
    for (int c = 0; c < 14; ++c) { float d = v[c] - mean; s2 = fmaf(d, d, s2); }
    #pragma unroll
    for (int off = 8; off; off >>= 1) s2 += __shfl_xor(s2, off, 16);
    float rs = rsqrtf(s2 * (1.f / 224.f) + 1e-6f);
    #pragma unroll
    for (int c = 0; c < 14; ++c) {
      int cc = l + 16 * c;
      ln_s[row * 232 + cc] = f2bf((v[c] - mean) * rs * g2[cc] + b2[cc]);
    }
  }
  __syncthreads();
  int wave = tid >> 6, lane = tid & 63;
  int nl = lane & 31, half = lane >> 5;
  int g1_t0 = (wave < 4) ? wave * 4 : 16 + (wave - 4) * 3;
  int g1_cnt = (wave < 4) ? 4 : 3;
  for (int i = 0; i < g1_cnt; ++i) {
    int nt = g1_t0 + i;
    f32x16 acc = {0.f,0.f,0.f,0.f,0.f,0.f,0.f,0.f,0.f,0.f,0.f,0.f,0.f,0.f,0.f,0.f};
    #pragma unroll
    for (int kt = 0; kt < 14; ++kt) {
      short8 a = *(const short8*)&ln_s[nl * 232 + kt * 16 + half * 8];
      short8 bw = *(const short8*)(m1F + ((size_t)(nt * 14 + kt) * 64 + lane) * 8);
      acc = __builtin_amdgcn_mfma_f32_32x32x16_bf16(a, bw, acc, 0, 0, 0);
    }
    int col = nt * 32 + nl;
    float bi = b1[col];
    #pragma unroll
    for (int r = 0; r < 16; ++r) {
      int row = (r & 3) + 8 * (r >> 2) + 4 * half;
      hid_s[row * 904 + col] = f2bf(gelu_exact(acc[r] + bi));
    }
  }
  __syncthreads();
  if (wave < 7) {
    int nt = wave;
    f32x16 ac0 = {0.f,0.f,0.f,0.f,0.f,0.f,0.f,0.f,0.f,0.f,0.f,0.f,0.f,0.f,0.f,0.f};
    f32x16 ac1 = {0.f,0.f,0.f,0.f,0.f,0.f,0.f,0.f,0.f,0.f,0.f,0.f,0.f,0.f,0.f,0.f};
    #pragma unroll 4
    for (int kt = 0; kt < 56; kt += 2) {
      short8 a0 = *(const short8*)&hid_s[nl * 904 + kt * 16 + half * 8];
      short8 a1 = *(const short8*)&hid_s[nl * 904 + (kt + 1) * 16 + half * 8];
      short8 b0 = *(const short8*)(m2F + ((size_t)(nt * 56 + kt) * 64 + lane) * 8);
      short8 b1 = *(const short8*)(m2F + ((size_t)(nt * 56 + kt + 1) * 64 + lane) * 8);
      ac0 = __builtin_amdgcn_mfma_f32_32x32x16_bf16(a0, b0, ac0, 0, 0, 0);
      ac1 = __builtin_amdgcn_mfma_f32_32x32x16_bf16(a1, b1, ac1, 0, 0, 0);
    }
    int col = nt * 32 + nl;
    float bi = b2b[col];
    #pragma unroll
    for (int r = 0; r < 16; ++r) {
      int row = (r & 3) + 8 * (r >> 2) + 4 * half;
      size_t idx = base + (size_t)row * 224 + col;
      out[idx] = hs2[idx] + ac0[r] + ac1[r] + bi;
    }
  }
}

extern "C" void kernel_launch(void* const* d_in, const int* in_sizes, int n_in,
                              void* d_out, int out_size, void* d_ws, size_t ws_size,
                              hipStream_t stream) {
  const float* x    = (const float*)d_in[0];
  const float* ln1g = (const float*)d_in[1];
  const float* ln1b = (const float*)d_in[2];
  const float* qkvw = (const float*)d_in[3];
  const float* qkvb = (const float*)d_in[4];
  const float* apw  = (const float*)d_in[5];
  const float* apb  = (const float*)d_in[6];
  const float* rpw  = (const float*)d_in[7];
  const float* rpb  = (const float*)d_in[8];
  const float* ln2g = (const float*)d_in[9];
  const float* ln2b = (const float*)d_in[10];
  const float* w1   = (const float*)d_in[11];
  const float* b1   = (const float*)d_in[12];
  const float* w2   = (const float*)d_in[13];
  const float* b2   = (const float*)d_in[14];
  float* out = (float*)d_out;

  short* hs_bf = (short*)d_ws;
  float* hs2   = (float*)((char*)d_ws + 29360128);
  short* o_bf  = (short*)((char*)d_ws + 58720256);
  short* wF    = (short*)((char*)d_ws + 73400320);

  cast_w_kernel<<<1024, 256, 0, stream>>>(qkvw, rpw, apw, w1, w2, wF);
  ln1_kernel<<<32768, 256, 0, stream>>>(x, ln1g, ln1b, hs_bf);
  respool_kernel<<<2048, 256, 0, stream>>>(hs_bf, wF + 90112, rpb, hs2);
  attn_kernel<<<2048, 256, 0, stream>>>(hs_bf, wF, qkvb, o_bf);
  aproj_kernel<<<512, 256, 0, stream>>>(o_bf, wF + 118784, apb, hs2);
  mlp_kernel<<<1024, 512, 0, stream>>>(hs2, ln2g, ln2b, wF + 168960, b1,
                                       wF + 369664, b2, out);
}